// Round 8
// baseline (646.831 us; speedup 1.0000x reference)
//
#include <hip/hip_runtime.h>

typedef unsigned short u16;
typedef unsigned int u32;
typedef __attribute__((ext_vector_type(4))) float f32x4;
typedef __bf16 bf16x8 __attribute__((ext_vector_type(8)));
typedef __attribute__((ext_vector_type(8))) unsigned short u16x8;

// ---------- small helpers ----------
__device__ __forceinline__ u16 f2bf(float x) {
    u32 u = __builtin_bit_cast(u32, x);
    u += 0x7FFFu + ((u >> 16) & 1u);   // RNE
    return (u16)(u >> 16);
}
__device__ __forceinline__ float bf2f(u16 u) {
    return __builtin_bit_cast(float, ((u32)u) << 16);
}
__device__ __forceinline__ void gld_lds16(void* lds, const void* g) {
    __builtin_amdgcn_global_load_lds(
        (const __attribute__((address_space(1))) void*)g,
        (__attribute__((address_space(3))) void*)lds, 16, 0, 0);
}

// bf16 pack locations inside an output row (u16 index into d_out viewed as u16).
// Row byte stride 201028 ≡ 4 (mod 16); "- ((row*2)&7)" u16s makes base 16B-aligned.
__device__ __forceinline__ size_t pack_base_tail(long row) {
    return (size_t)row * 100514 + 59936 - ((row * 2) & 7);
}
__device__ __forceinline__ size_t pack_base_head(long row) {
    return (size_t)row * 100514 + 20480 - ((row * 2) & 7);
}

// ---------- all f32->bf16 converts + zero-pads in one kernel ----------
__global__ __launch_bounds__(256) void cvt_all(const float* __restrict__ x,
                                               const float* __restrict__ hw,
                                               const float* __restrict__ t0a,
                                               const float* __restrict__ t1a,
                                               const float* __restrict__ t0b,
                                               const float* __restrict__ t1b,
                                               u16* __restrict__ XI, u16* __restrict__ HW,
                                               u16* __restrict__ TAB, u16* __restrict__ T0B,
                                               u16* __restrict__ T1B) {
    int b = blockIdx.x;
    const float* src; u16* dst; int n, b0, nb;
    if (b < 80)        { src = x;    dst = XI;            n = 2097152;  b0 = 0;    nb = 80;   }
    else if (b < 472)  { src = hw;   dst = HW;            n = 10242048; b0 = 80;   nb = 392;  }
    else if (b < 512)  { src = t0a;  dst = TAB;           n = 1048576;  b0 = 472;  nb = 40;   }
    else if (b < 522)  { src = t1a;  dst = TAB + 1048576; n = 262144;   b0 = 512;  nb = 10;   }
    else if (b < 2086) { src = t0b;  dst = T0B;           n = 40960000; b0 = 522;  nb = 1564; }
    else if (b < 2090) { src = t1b;  dst = T1B;           n = 65792;    b0 = 2086; nb = 4;    }
    else if (b < 2100) { src = 0;    dst = HW + 10242048; n = 243712;   b0 = 2090; nb = 10;   }
    else               { src = 0;    dst = T0B + 40960000; n = 196608;  b0 = 2100; nb = 8;    }
    int i0 = (b - b0) * 1024 + threadIdx.x * 4;
    int stride = nb * 1024;
    if (src) {
        for (int i = i0; i < n; i += stride) {
            float4 v = *(const float4*)(src + i);
            ushort4 o;
            o.x = f2bf(v.x); o.y = f2bf(v.y); o.z = f2bf(v.z); o.w = f2bf(v.w);
            *(ushort4*)(dst + i) = o;
        }
    } else {
        ushort4 z = {0, 0, 0, 0};
        for (int i = i0; i < n; i += stride) *(ushort4*)(dst + i) = z;
    }
}

// ---------- build compact row map (1 block) ----------
// rowlist[0..cnt) = masked rows asc; rowlist[cnt..2048) = unmasked rows asc.
// cntbuf: [0]=cnt, [1]=cnt padded to 128
__global__ __launch_bounds__(256) void build_map(const int* __restrict__ tgt,
                                                 int* __restrict__ rowlist,
                                                 int* __restrict__ cntbuf) {
    __shared__ int cs[257];
    int t = threadIdx.x;
    int cnt_local = 0;
    int mk[8];
#pragma unroll
    for (int k = 0; k < 8; k++) {
        int tg = tgt[t * 8 + k];
        mk[k] = (tg >= 10000 && tg < 50000) ? 1 : 0;
        cnt_local += mk[k];
    }
    cs[t + 1] = cnt_local;
    __syncthreads();
    if (t == 0) {
        cs[0] = 0;
        for (int i = 1; i <= 256; i++) cs[i] += cs[i - 1];
        cntbuf[0] = cs[256];
        cntbuf[1] = (cs[256] + 127) & ~127;
    }
    __syncthreads();
    int cnt = cs[256];
    int offm = cs[t];
    int offu = cnt + (t * 8 - cs[t]);
#pragma unroll
    for (int k = 0; k < 8; k++) {
        if (mk[k]) rowlist[offm++] = t * 8 + k;
        else       rowlist[offu++] = t * 8 + k;
    }
}

// ---------- 128x256 BK=32 8-wave m97-simple NT bf16 GEMM, 2 blocks/CU ----------
// No inline asm: __syncthreads(); stage (3 gld_lds); __syncthreads(); ds_read + MFMA.
// Compiler emits counted lgkmcnt inside compute; co-resident block hides stage drain.
// XCD swizzle: linear l -> w=(l%8)*(nwg/8)+l/8 (nwg%8==0, bijective); mblk=w&15, nblk=w>>4
// so each B-panel's 16 M-blocks are contiguous on one XCD.
// LDS subtile layout (conflict-free, R4-R7-proven): chunk c (16B) at byte c*16 holds
// (row=(c>>6<<4)+(c&15), k8=(c>>4)&3); frag (R,kc=hi): u16 off (R>>4)*512+hi*128+(R&15)*8.
// A region bytes [0,8192), B region bytes [8192,24576).
template <int TAIL>
__global__ __launch_bounds__(512, 4) void gemm128(const u16* __restrict__ A,
                                                  const u16* __restrict__ B,
                                                  u16* __restrict__ outpk,
                                                  const int* __restrict__ rowlist,
                                                  const int* __restrict__ cntbuf,
                                                  float* __restrict__ part) {
    const int NB = TAIL ? 157 : 40;
    const int nwg = 16 * NB;
    const int l = blockIdx.y * 16 + blockIdx.x;
    const int w = (l & 7) * (nwg >> 3) + (l >> 3);
    const int mblk = w & 15, nblk = w >> 4;
    const int m0 = mblk * 128, n0 = nblk * 256;
    if (TAIL) { if (m0 >= cntbuf[1]) return; }
    __shared__ u16 lds[12288];   // A 8KB + B 16KB = 24KB -> 2 blocks/CU (with VGPR<=128)
    const int tid = threadIdx.x;
    const int lane = tid & 63, wv = tid >> 6;
    const int wm = wv >> 2, wn = wv & 3;      // 2x4 wave grid, wave tile 64x64
    const int lr = lane & 15, hi = lane >> 4;

    // staging sources: A chunk = tid; B chunks = tid, tid+512
    const int ra = ((tid >> 6) << 4) + (tid & 15);
    const int ka = ((tid >> 4) & 3) * 8;
    const u16* sA = TAIL ? A + (size_t)rowlist[m0 + ra] * 1280 + ka
                         : A + (size_t)(m0 + ra) * 1024 + ka;
    const int c1 = tid + 512;
    const u16* sB0 = B + (size_t)(n0 + ra) * 1024 + ka;
    const u16* sB1 = B + (size_t)(n0 + ((c1 >> 6) << 4) + (c1 & 15)) * 1024 + ((c1 >> 4) & 3) * 8;

    f32x4 acc[4][4] = {};

#pragma unroll 1
    for (int kt = 0; kt < 1024; kt += 32) {
        __syncthreads();                       // prev-tile reads done (lgkmcnt drained)
        char* d = (char*)lds + tid * 16;
        gld_lds16(d,         sA + kt);
        gld_lds16(d + 8192,  sB0 + kt);
        gld_lds16(d + 16384, sB1 + kt);
        __syncthreads();                       // vmcnt(0) drained -> tile resident

        bf16x8 Bf[4];
#pragma unroll
        for (int j = 0; j < 4; j++)
            Bf[j] = *(const bf16x8*)(lds + 4096 + (wn * 4 + j) * 512 + hi * 128 + lr * 8);
#pragma unroll
        for (int m = 0; m < 4; m++) {
            bf16x8 Af = *(const bf16x8*)(lds + (wm * 4 + m) * 512 + hi * 128 + lr * 8);
#pragma unroll
            for (int j = 0; j < 4; j++)
                acc[m][j] = __builtin_amdgcn_mfma_f32_16x16x32_bf16(Af, Bf[j], acc[m][j], 0, 0, 0);
        }
    }

    // epilogue: bf16 pack scatter + per-64col exp-sum partials
    const int cr = hi * 4, cc = lr;
    const int climit = TAIL ? 40000 : 10002;
    const int pstride = TAIL ? 628 : 160;
#pragma unroll
    for (int m = 0; m < 4; m++) {
#pragma unroll
        for (int q = 0; q < 4; q++) {
            int r = m0 + wm * 64 + m * 16 + cr + q;
            long orow = TAIL ? rowlist[r] : r;
            size_t base = TAIL ? pack_base_tail(orow) : pack_base_head(orow);
            u16* dst = outpk + base + n0 + wn * 64 + cc;
            float s = 0.f;
#pragma unroll
            for (int j = 0; j < 4; j++) {
                float v = acc[m][j][q];
                dst[j * 16] = f2bf(v);
                int col = n0 + wn * 64 + j * 16 + cc;
                s += (col < climit) ? __expf(v) : 0.f;
            }
            s += __shfl_xor(s, 1); s += __shfl_xor(s, 2);
            s += __shfl_xor(s, 4); s += __shfl_xor(s, 8);
            if (cc == 0) part[(size_t)r * pstride + (n0 >> 6) + wn] = s;
        }
    }
}

// ---------- 128x128 NT bf16 GEMM (m97 structure) for proj ----------
__global__ __launch_bounds__(256) void gemm_nt_bf16(const u16* __restrict__ A, int lda,
                                                    const u16* __restrict__ B, int ldb,
                                                    u16* __restrict__ Cb, long ldc, int K) {
    __shared__ u16 lA[128 * 32];
    __shared__ u16 lB[128 * 32];
    const int tid = threadIdx.x;
    const int lane = tid & 63, wv = tid >> 6;
    const int m0 = blockIdx.x * 128, n0 = blockIdx.y * 128;

    const u16* gA0 = A + (size_t)(m0 + (tid >> 2)) * lda + (tid & 3) * 8;
    const u16* gB0 = B + (size_t)(n0 + (tid >> 2)) * ldb + (tid & 3) * 8;
    char* dA = (char*)lA + wv * 1024;
    char* dB = (char*)lB + wv * 1024;

    f32x4 acc[4][4] = {};
    const int wm = wv >> 1, wn = wv & 1;
    const int lr = lane & 15;
    const int lk = (lane >> 4) * 8;

    for (int kt = 0; kt < K; kt += 32) {
        __syncthreads();
        gld_lds16(dA, gA0);
        gld_lds16(dA + 4096, gA0 + 64 * (size_t)lda);
        gld_lds16(dB, gB0);
        gld_lds16(dB + 4096, gB0 + 64 * (size_t)ldb);
        gA0 += 32; gB0 += 32;
        __syncthreads();

        bf16x8 af[4], bfr[4];
#pragma unroll
        for (int i = 0; i < 4; i++) {
            af[i]  = *(const bf16x8*)(lA + (wm * 64 + i * 16 + lr) * 32 + lk);
            bfr[i] = *(const bf16x8*)(lB + (wn * 64 + i * 16 + lr) * 32 + lk);
        }
#pragma unroll
        for (int i = 0; i < 4; i++)
#pragma unroll
            for (int j = 0; j < 4; j++)
                acc[i][j] = __builtin_amdgcn_mfma_f32_16x16x32_bf16(af[i], bfr[j], acc[i][j], 0, 0, 0);
    }

    const int cr = (lane >> 4) * 4;
    const int cc = lane & 15;
#pragma unroll
    for (int i = 0; i < 4; i++) {
        int rbase = m0 + wm * 64 + i * 16 + cr;
#pragma unroll
        for (int j = 0; j < 4; j++) {
            int c = n0 + wn * 64 + j * 16 + cc;
#pragma unroll
            for (int q = 0; q < 4; q++)
                Cb[(size_t)(rbase + q) * (size_t)ldc + c] = f2bf(acc[i][j][q]);
        }
    }
}

// ---------- head: reduce partials -> logZ; expand bf16 pack -> f32 lp; save stats ----------
// stats per row (8 f32): [0]=prior0(lp[9999]) [1]=prior1(lp[10000]) [2]=lp[10000] [3]=lp[10001]
__global__ __launch_bounds__(256) void head_norm(float* __restrict__ out,
                                                 float* __restrict__ stats,
                                                 const float* __restrict__ parth) {
    const int row = blockIdx.x, tid = threadIdx.x;
    float s = (tid < 160) ? parth[(size_t)row * 160 + tid] : 0.f;
#pragma unroll
    for (int o = 32; o; o >>= 1) s += __shfl_xor(s, o);
    __shared__ float red[4];
    if ((tid & 63) == 0) red[tid >> 6] = s;
    __syncthreads();
    float logZ = __logf(red[0] + red[1] + red[2] + red[3]);
    const u16* pk = (const u16*)out + pack_base_head(row);
    float* p = out + (size_t)row * 50257;
    for (int k = 0; k < 5; k++) {
        int c0 = k * 2048 + tid * 8;
        if (c0 + 8 <= 10002) {
            u16x8 xv = *(const u16x8*)(pk + c0);
#pragma unroll
            for (int z = 0; z < 8; z++) p[c0 + z] = bf2f(xv[z]) - logZ;
        } else if (c0 < 10002) {
            for (int z = 0; c0 + z < 10002; z++) p[c0 + z] = bf2f(pk[c0 + z]) - logZ;
        }
    }
    if (tid == 0) {
        float* st = stats + row * 8;
        float l0 = bf2f(pk[9999]) - logZ;
        float l1 = bf2f(pk[10000]) - logZ;
        float l2 = bf2f(pk[10001]) - logZ;
        st[0] = l0; st[1] = l1; st[2] = l1; st[3] = l2;
    }
}

// ---------- tail0: reduce partials + in-place expand+normalize / zero-fill ----------
__global__ __launch_bounds__(256) void tail0_norm(float* __restrict__ out,
                                                  const int* __restrict__ rowlist,
                                                  const int* __restrict__ cntbuf,
                                                  const float* __restrict__ ST,
                                                  const float* __restrict__ PART) {
    const int b = blockIdx.x, tid = threadIdx.x;
    const int cnt = cntbuf[0];
    const long row = rowlist[b];
    float* p = out + (size_t)row * 50257 + 10000;
    __shared__ float red[4];
    if (b < cnt) {
        float s = 0.f;
        for (int c = tid; c < 628; c += 256) s += PART[(size_t)b * 628 + c];
#pragma unroll
        for (int o = 32; o; o >>= 1) s += __shfl_xor(s, o);
        if ((tid & 63) == 0) red[tid >> 6] = s;
        __syncthreads();
        float Aa = __logf(red[0] + red[1] + red[2] + red[3]) - ST[row * 8 + 0];
        const u16* src = (const u16*)out + pack_base_tail(row);
        for (int k = 0; k < 5; k++) {
            float v[4][8];
#pragma unroll
            for (int g = 0; g < 4; g++) {
                int o = 2048 * g + tid * 8;
                if (o < 8000) {
                    u16x8 xv = *(const u16x8*)(src + 8000 * k + o);
#pragma unroll
                    for (int z = 0; z < 8; z++) v[g][z] = bf2f(xv[z]);
                }
            }
            __syncthreads();
#pragma unroll
            for (int g = 0; g < 4; g++) {
                int o = 2048 * g + tid * 8;
                if (o < 8000) {
                    int e = 8000 * k + o;
#pragma unroll
                    for (int z = 0; z < 8; z++) p[e + z] = v[g][z] - Aa;
                }
            }
            __syncthreads();
        }
    } else {
        float v0 = ST[row * 8 + 2], v1 = ST[row * 8 + 3];
        for (int e = tid; e < 40000; e += 256) p[e] = 0.f;
        if (tid == 0) { p[0] = v0; p[1] = v1; }
    }
}

// ---------- tail1: tiny GEMM + log_softmax + masked write for cols [50000,50257) ----------
__global__ __launch_bounds__(256) void tail1_kernel(float* __restrict__ out,
                                                    const int* __restrict__ tgt,
                                                    const u16* __restrict__ proj,
                                                    const u16* __restrict__ t1b,
                                                    const float* __restrict__ stats) {
    const int row = blockIdx.x, tid = threadIdx.x;
    float* p = out + (size_t)row * 50257 + 50000;
    int t = tgt[row];
    if (t < 50000) {
        for (int c = tid; c < 257; c += 256) p[c] = 0.f;
        return;
    }
    __shared__ float pr[256];
    __shared__ float lg[257];
    __shared__ float red[4];
    pr[tid] = bf2f(proj[(size_t)row * 1280 + 1024 + tid]);
    __syncthreads();
    for (int c = tid; c < 257; c += 256) {
        const u16* w = t1b + c * 256;
        float acc = 0.f;
        for (int k = 0; k < 256; k++) acc += bf2f(w[k]) * pr[k];
        lg[c] = acc;
    }
    __syncthreads();
    float s = 0.f;
    for (int c = tid; c < 257; c += 256) s += __expf(lg[c]);
#pragma unroll
    for (int o = 32; o; o >>= 1) s += __shfl_xor(s, o);
    if ((tid & 63) == 0) red[tid >> 6] = s;
    __syncthreads();
    float A = __logf(red[0] + red[1] + red[2] + red[3]) - stats[row * 8 + 1];  // logZ - prior1
    for (int c = tid; c < 257; c += 256) p[c] = lg[c] - A;
}

// ---------- workspace layout (bytes) ----------
#define OFF_XI    0UL              // 2048*1024*2    = 4,194,304
#define OFF_HEADW 4194304UL        // 10240*1024*2   = 20,971,520
#define OFF_TAB   25165824UL       // 1280*1024*2    = 2,621,440
#define OFF_T0B   27787264UL       // 40192*1024*2   = 82,313,216
#define OFF_T1B   110100480UL      // 257*256*2      = 131,584
#define OFF_PROJ  110232064UL      // 2048*1280*2    = 5,242,880
#define OFF_ST    115474944UL      // 2048*8*4       = 65,536
#define OFF_PART  115540480UL      // 2048*628*4     = 5,144,576
#define OFF_PARTH 120685056UL      // 2048*160*4     = 1,310,720
#define OFF_MAP   121995776UL      // 2048*4
#define OFF_CNT   122003968UL      // 64

extern "C" void kernel_launch(void* const* d_in, const int* in_sizes, int n_in,
                              void* d_out, int out_size, void* d_ws, size_t ws_size,
                              hipStream_t stream) {
    const float* x   = (const float*)d_in[0];
    const int*   tgt = (const int*)d_in[1];
    const float* hw  = (const float*)d_in[2];
    const float* t0a = (const float*)d_in[3];
    const float* t0b = (const float*)d_in[4];
    const float* t1a = (const float*)d_in[5];
    const float* t1b = (const float*)d_in[6];
    float* out = (float*)d_out;
    char* ws = (char*)d_ws;

    u16* XI     = (u16*)(ws + OFF_XI);
    u16* HW     = (u16*)(ws + OFF_HEADW);
    u16* TAB    = (u16*)(ws + OFF_TAB);
    u16* T0B    = (u16*)(ws + OFF_T0B);
    u16* T1B    = (u16*)(ws + OFF_T1B);
    u16* PROJ   = (u16*)(ws + OFF_PROJ);
    float* ST   = (float*)(ws + OFF_ST);
    float* PART = (float*)(ws + OFF_PART);
    float* PARTH = (float*)(ws + OFF_PARTH);
    int* MAP    = (int*)(ws + OFF_MAP);
    int* CNT    = (int*)(ws + OFF_CNT);

    // 1) all converts + pads (one kernel)
    cvt_all<<<2108, 256, 0, stream>>>(x, hw, t0a, t1a, t0b, t1b, XI, HW, TAB, T0B, T1B);

    // 2) row map (padded to 128)
    build_map<<<1, 256, 0, stream>>>(tgt, MAP, CNT);

    // 3) head GEMM (128x256 m97-simple, 2 blocks/CU, XCD-swizzled): bf16 pack + exp partials
    gemm128<0><<<dim3(16, 40), 512, 0, stream>>>(XI, HW, (u16*)d_out, nullptr, nullptr, PARTH);

    // 4) head: logZ + expand to f32 lp + stats
    head_norm<<<2048, 256, 0, stream>>>(out, ST, PARTH);

    // 5) proj GEMM: [xi @ t0a.T | xi @ t1a.T] -> bf16 (2048 x 1280)
    gemm_nt_bf16<<<dim3(16, 10), 256, 0, stream>>>(XI, 1024, TAB, 1024, PROJ, 1280L, 1024);

    // 6) tail0 GEMM (128x256 m97-simple, 2 blocks/CU, XCD-swizzled, rowlist-gathered A)
    gemm128<1><<<dim3(16, 157), 512, 0, stream>>>(PROJ, T0B, (u16*)d_out, MAP, CNT, PART);

    // 7) fused reduce + expand/normalize (masked) / zero-fill (unmasked)
    tail0_norm<<<2048, 256, 0, stream>>>(out, MAP, CNT, ST, PART);

    // 8) tail1
    tail1_kernel<<<2048, 256, 0, stream>>>(out, tgt, PROJ, T1B, ST);
}

// Round 9
// 567.057 us; speedup vs baseline: 1.1407x; 1.1407x over previous
//
#include <hip/hip_runtime.h>

typedef unsigned short u16;
typedef unsigned int u32;
typedef __attribute__((ext_vector_type(4))) float f32x4;
typedef __bf16 bf16x8 __attribute__((ext_vector_type(8)));
typedef __attribute__((ext_vector_type(8))) unsigned short u16x8;

// ---------- small helpers ----------
__device__ __forceinline__ u16 f2bf(float x) {
    u32 u = __builtin_bit_cast(u32, x);
    u += 0x7FFFu + ((u >> 16) & 1u);   // RNE
    return (u16)(u >> 16);
}
__device__ __forceinline__ float bf2f(u16 u) {
    return __builtin_bit_cast(float, ((u32)u) << 16);
}
__device__ __forceinline__ void gld_lds16(void* lds, const void* g) {
    __builtin_amdgcn_global_load_lds(
        (const __attribute__((address_space(1))) void*)g,
        (__attribute__((address_space(3))) void*)lds, 16, 0, 0);
}

// bf16 pack locations inside an output row (u16 index into d_out viewed as u16).
__device__ __forceinline__ size_t pack_base_tail(long row) {
    return (size_t)row * 100514 + 59936 - ((row * 2) & 7);
}
__device__ __forceinline__ size_t pack_base_head(long row) {
    return (size_t)row * 100514 + 20480 - ((row * 2) & 7);
}

// ---------- all f32->bf16 converts + zero-pads in one kernel ----------
__global__ __launch_bounds__(256) void cvt_all(const float* __restrict__ x,
                                               const float* __restrict__ hw,
                                               const float* __restrict__ t0a,
                                               const float* __restrict__ t1a,
                                               const float* __restrict__ t0b,
                                               const float* __restrict__ t1b,
                                               u16* __restrict__ XI, u16* __restrict__ HW,
                                               u16* __restrict__ TAB, u16* __restrict__ T0B,
                                               u16* __restrict__ T1B) {
    int b = blockIdx.x;
    const float* src; u16* dst; int n, b0, nb;
    if (b < 80)        { src = x;    dst = XI;            n = 2097152;  b0 = 0;    nb = 80;   }
    else if (b < 472)  { src = hw;   dst = HW;            n = 10242048; b0 = 80;   nb = 392;  }
    else if (b < 512)  { src = t0a;  dst = TAB;           n = 1048576;  b0 = 472;  nb = 40;   }
    else if (b < 522)  { src = t1a;  dst = TAB + 1048576; n = 262144;   b0 = 512;  nb = 10;   }
    else if (b < 2086) { src = t0b;  dst = T0B;           n = 40960000; b0 = 522;  nb = 1564; }
    else if (b < 2090) { src = t1b;  dst = T1B;           n = 65792;    b0 = 2086; nb = 4;    }
    else if (b < 2100) { src = 0;    dst = HW + 10242048; n = 243712;   b0 = 2090; nb = 10;   }
    else               { src = 0;    dst = T0B + 40960000; n = 196608;  b0 = 2100; nb = 8;    }
    int i0 = (b - b0) * 1024 + threadIdx.x * 4;
    int stride = nb * 1024;
    if (src) {
        for (int i = i0; i < n; i += stride) {
            float4 v = *(const float4*)(src + i);
            ushort4 o;
            o.x = f2bf(v.x); o.y = f2bf(v.y); o.z = f2bf(v.z); o.w = f2bf(v.w);
            *(ushort4*)(dst + i) = o;
        }
    } else {
        ushort4 z = {0, 0, 0, 0};
        for (int i = i0; i < n; i += stride) *(ushort4*)(dst + i) = z;
    }
}

// ---------- build compact row map (1 block) ----------
// rowlist[0..cnt) = masked rows asc; rowlist[cnt..2048) = unmasked rows asc.
// cntbuf: [0]=cnt, [1]=cnt padded to 256
__global__ __launch_bounds__(256) void build_map(const int* __restrict__ tgt,
                                                 int* __restrict__ rowlist,
                                                 int* __restrict__ cntbuf) {
    __shared__ int cs[257];
    int t = threadIdx.x;
    int cnt_local = 0;
    int mk[8];
#pragma unroll
    for (int k = 0; k < 8; k++) {
        int tg = tgt[t * 8 + k];
        mk[k] = (tg >= 10000 && tg < 50000) ? 1 : 0;
        cnt_local += mk[k];
    }
    cs[t + 1] = cnt_local;
    __syncthreads();
    if (t == 0) {
        cs[0] = 0;
        for (int i = 1; i <= 256; i++) cs[i] += cs[i - 1];
        cntbuf[0] = cs[256];
        cntbuf[1] = (cs[256] + 255) & ~255;
    }
    __syncthreads();
    int cnt = cs[256];
    int offm = cs[t];
    int offu = cnt + (t * 8 - cs[t]);
#pragma unroll
    for (int k = 0; k < 8; k++) {
        if (mk[k]) rowlist[offm++] = t * 8 + k;
        else       rowlist[offu++] = t * 8 + k;
    }
}

// ---------- 256x256 BK=64 8-wave, m201-style 8-phase NT bf16 GEMM ----------
// LDS 128KiB: SA[2] (u16 [0,16384),[16384,32768)), SB[2] ([32768..),[49152..)).
// Tile t lives in slot t&1. 8 phases per 2 K-tiles; B-frags read once per tile
// (P1/P5), HELD in regs 4 phases; A-frags (4 ds_read) per phase; stages spread
// 1-2 half-tiles per phase into slots freed >=1 barrier earlier; vmcnt(4) only
// at P4/P8. Per-phase fence: bar; lgkmcnt(0); sched_barrier(0); setprio(1);
// 16 MFMA; setprio(0); bar.  (rule 18 + T3/T4/T5 per guide)
// Half layout (128 rows x 64 k): chunk c (16B) at byte c*16 = row ((c>>7)*16+(c&15)),
// k ((c>>4)&7)*8; frag read (R, kg): u16 off (R>>4)*1024 + kg*128 + (R&15)*8.
template <int TAIL>
__global__ __launch_bounds__(512, 1) void gemm256p(const u16* __restrict__ A,
                                                   const u16* __restrict__ B,
                                                   u16* __restrict__ outpk,
                                                   const int* __restrict__ rowlist,
                                                   const int* __restrict__ cntbuf,
                                                   float* __restrict__ part) {
    const int NY = TAIL ? 157 : 40;
    const int l = blockIdx.y * 8 + blockIdx.x;
    const int w = (l & 7) * NY + (l >> 3);
    const int m0 = (w & 7) * 256, n0 = (w >> 3) * 256;
    if (TAIL) { if (m0 >= cntbuf[1]) return; }
    __shared__ u16 lds[65536];
    const int tid = threadIdx.x;
    const int lane = tid & 63, wv = tid >> 6;
    const int wm = wv >> 2, wn = wv & 3;      // 2x4 wave grid, wave tile 128x64
    const int lr = lane & 15, hi = lane >> 4;

    // staging geometry: thread covers chunks tid (row rp) and tid+512 (row rp+64),
    // same k-group kp, of each 128x64 half.
    const int rp = ((tid >> 7) << 4) + (tid & 15);
    const int kp = ((tid >> 4) & 7) * 8;
    const u16 *pA[2][2], *pB[2][2];  // [half][chunk]
#pragma unroll
    for (int h = 0; h < 2; h++) {
#pragma unroll
        for (int c = 0; c < 2; c++) {
            int row = h * 128 + rp + c * 64;
            if (TAIL) pA[h][c] = A + (size_t)rowlist[m0 + row] * 1280 + kp;
            else      pA[h][c] = A + (size_t)(m0 + row) * 1024 + kp;
            pB[h][c] = B + (size_t)(n0 + row) * 1024 + kp;
        }
    }

    f32x4 acc[8][4] = {};
    bf16x8 Bf[4][2], Af[2][2];

    auto stA = [&](int s, int h, int t) {
        u16* d = lds + s * 16384 + h * 8192 + tid * 8;
        int ko = t * 64;
        gld_lds16(d, pA[h][0] + ko);
        gld_lds16(d + 4096, pA[h][1] + ko);
    };
    auto stB = [&](int s, int h, int t) {
        u16* d = lds + 32768 + s * 16384 + h * 8192 + tid * 8;
        int ko = t * 64;
        gld_lds16(d, pB[h][0] + ko);
        gld_lds16(d + 4096, pB[h][1] + ko);
    };
    auto rdB = [&](int s) {
        const u16* base = lds + 32768 + s * 16384 + (wn >> 1) * 8192 + (wn & 1) * 4096 + hi * 128 + lr * 8;
#pragma unroll
        for (int j = 0; j < 4; j++)
#pragma unroll
            for (int ks = 0; ks < 2; ks++)
                Bf[j][ks] = *(const bf16x8*)(base + j * 1024 + ks * 512);
    };
    auto rdA = [&](int s, int p) {
        const u16* base = lds + s * 16384 + wm * 8192 + p * 2048 + hi * 128 + lr * 8;
#pragma unroll
        for (int m = 0; m < 2; m++)
#pragma unroll
            for (int ks = 0; ks < 2; ks++)
                Af[m][ks] = *(const bf16x8*)(base + m * 1024 + ks * 512);
    };
    auto mf = [&](int p) {
        __builtin_amdgcn_s_setprio(1);
#pragma unroll
        for (int m = 0; m < 2; m++)
#pragma unroll
            for (int j = 0; j < 4; j++)
#pragma unroll
                for (int ks = 0; ks < 2; ks++)
                    acc[p * 2 + m][j] = __builtin_amdgcn_mfma_f32_16x16x32_bf16(
                        Af[m][ks], Bf[j][ks], acc[p * 2 + m][j], 0, 0, 0);
        __builtin_amdgcn_s_setprio(0);
    };

#define BAR_()   __builtin_amdgcn_s_barrier()
#define LGKM0_() do { asm volatile("s_waitcnt lgkmcnt(0)" ::: "memory"); \
                      __builtin_amdgcn_sched_barrier(0); } while (0)
#define VM4_()   asm volatile("s_waitcnt vmcnt(4)" ::: "memory")
#define VM0_()   asm volatile("s_waitcnt vmcnt(0)" ::: "memory")

    // prologue: tile0 fully staged + drained; B(1) issued (in flight across barrier)
    stA(0, 0, 0); stA(0, 1, 0); stB(0, 0, 0); stB(0, 1, 0);
    VM0_();
    stB(1, 0, 1); stB(1, 1, 1);
    BAR_();

    auto iter = [&](int t0, bool full) {   // computes tiles t0 (slot0), t0+1 (slot1)
        // P1
        rdB(0); rdA(0, 0);
        stA(1, 0, t0 + 1);
        BAR_(); LGKM0_(); mf(0); BAR_();
        // P2
        rdA(0, 1);
        stA(1, 1, t0 + 1);
        __builtin_amdgcn_sched_barrier(0);          // pin stage order for vmcnt math
        if (full) stB(0, 0, t0 + 2);
        BAR_(); LGKM0_(); mf(1); BAR_();
        // P3
        rdA(0, 2);
        if (full) stB(0, 1, t0 + 2);
        BAR_(); LGKM0_(); mf(2); BAR_();
        // P4: retire A(t0+1)+B(t0+1); leave B(t0+2) in flight
        rdA(0, 3);
        if (full) { VM4_(); } else { VM0_(); }
        BAR_(); LGKM0_(); mf(3); BAR_();
        // P5
        rdB(1); rdA(1, 0);
        if (full) stA(0, 0, t0 + 2);
        BAR_(); LGKM0_(); mf(0); BAR_();
        // P6
        rdA(1, 1);
        if (full) { stA(0, 1, t0 + 2);
                    __builtin_amdgcn_sched_barrier(0);
                    stB(1, 0, t0 + 3); }
        BAR_(); LGKM0_(); mf(1); BAR_();
        // P7
        rdA(1, 2);
        if (full) stB(1, 1, t0 + 3);
        BAR_(); LGKM0_(); mf(2); BAR_();
        // P8: retire A(t0+2); leave B(t0+3) in flight
        rdA(1, 3);
        if (full) VM4_();
        BAR_(); LGKM0_(); mf(3); BAR_();
    };
#pragma unroll 1
    for (int i = 0; i < 7; i++) iter(2 * i, true);
    iter(14, false);

#undef BAR_
#undef LGKM0_
#undef VM4_
#undef VM0_

    // epilogue: bf16 pack scatter + per-64col exp-sum partials
    const int cr = hi * 4, cc = lr;
    const int climit = TAIL ? 40000 : 10002;
    const int pstride = TAIL ? 628 : 160;
#pragma unroll
    for (int m = 0; m < 8; m++) {
#pragma unroll
        for (int q = 0; q < 4; q++) {
            int r = m0 + wm * 128 + m * 16 + cr + q;
            long orow = TAIL ? rowlist[r] : r;
            size_t base = TAIL ? pack_base_tail(orow) : pack_base_head(orow);
            u16* dst = outpk + base + n0 + wn * 64 + cc;
            float s = 0.f;
#pragma unroll
            for (int j = 0; j < 4; j++) {
                float v = acc[m][j][q];
                dst[j * 16] = f2bf(v);
                int col = n0 + wn * 64 + j * 16 + cc;
                s += (col < climit) ? __expf(v) : 0.f;
            }
            s += __shfl_xor(s, 1); s += __shfl_xor(s, 2);
            s += __shfl_xor(s, 4); s += __shfl_xor(s, 8);
            if (cc == 0) part[(size_t)r * pstride + (n0 >> 6) + wn] = s;
        }
    }
}

// ---------- 128x128 NT bf16 GEMM (m97 structure) for proj ----------
__global__ __launch_bounds__(256) void gemm_nt_bf16(const u16* __restrict__ A, int lda,
                                                    const u16* __restrict__ B, int ldb,
                                                    u16* __restrict__ Cb, long ldc, int K) {
    __shared__ u16 lA[128 * 32];
    __shared__ u16 lB[128 * 32];
    const int tid = threadIdx.x;
    const int lane = tid & 63, wv = tid >> 6;
    const int m0 = blockIdx.x * 128, n0 = blockIdx.y * 128;

    const u16* gA0 = A + (size_t)(m0 + (tid >> 2)) * lda + (tid & 3) * 8;
    const u16* gB0 = B + (size_t)(n0 + (tid >> 2)) * ldb + (tid & 3) * 8;
    char* dA = (char*)lA + wv * 1024;
    char* dB = (char*)lB + wv * 1024;

    f32x4 acc[4][4] = {};
    const int wm = wv >> 1, wn = wv & 1;
    const int lr = lane & 15;
    const int lk = (lane >> 4) * 8;

    for (int kt = 0; kt < K; kt += 32) {
        __syncthreads();
        gld_lds16(dA, gA0);
        gld_lds16(dA + 4096, gA0 + 64 * (size_t)lda);
        gld_lds16(dB, gB0);
        gld_lds16(dB + 4096, gB0 + 64 * (size_t)ldb);
        gA0 += 32; gB0 += 32;
        __syncthreads();

        bf16x8 af[4], bfr[4];
#pragma unroll
        for (int i = 0; i < 4; i++) {
            af[i]  = *(const bf16x8*)(lA + (wm * 64 + i * 16 + lr) * 32 + lk);
            bfr[i] = *(const bf16x8*)(lB + (wn * 64 + i * 16 + lr) * 32 + lk);
        }
#pragma unroll
        for (int i = 0; i < 4; i++)
#pragma unroll
            for (int j = 0; j < 4; j++)
                acc[i][j] = __builtin_amdgcn_mfma_f32_16x16x32_bf16(af[i], bfr[j], acc[i][j], 0, 0, 0);
    }

    const int cr = (lane >> 4) * 4;
    const int cc = lane & 15;
#pragma unroll
    for (int i = 0; i < 4; i++) {
        int rbase = m0 + wm * 64 + i * 16 + cr;
#pragma unroll
        for (int j = 0; j < 4; j++) {
            int c = n0 + wn * 64 + j * 16 + cc;
#pragma unroll
            for (int q = 0; q < 4; q++)
                Cb[(size_t)(rbase + q) * (size_t)ldc + c] = f2bf(acc[i][j][q]);
        }
    }
}

// ---------- head: reduce partials -> logZ; expand bf16 pack -> f32 lp; save stats ----------
__global__ __launch_bounds__(256) void head_norm(float* __restrict__ out,
                                                 float* __restrict__ stats,
                                                 const float* __restrict__ parth) {
    const int row = blockIdx.x, tid = threadIdx.x;
    float s = (tid < 160) ? parth[(size_t)row * 160 + tid] : 0.f;
#pragma unroll
    for (int o = 32; o; o >>= 1) s += __shfl_xor(s, o);
    __shared__ float red[4];
    if ((tid & 63) == 0) red[tid >> 6] = s;
    __syncthreads();
    float logZ = __logf(red[0] + red[1] + red[2] + red[3]);
    const u16* pk = (const u16*)out + pack_base_head(row);
    float* p = out + (size_t)row * 50257;
    for (int k = 0; k < 5; k++) {
        int c0 = k * 2048 + tid * 8;
        if (c0 + 8 <= 10002) {
            u16x8 xv = *(const u16x8*)(pk + c0);
#pragma unroll
            for (int z = 0; z < 8; z++) p[c0 + z] = bf2f(xv[z]) - logZ;
        } else if (c0 < 10002) {
            for (int z = 0; c0 + z < 10002; z++) p[c0 + z] = bf2f(pk[c0 + z]) - logZ;
        }
    }
    if (tid == 0) {
        float* st = stats + row * 8;
        float l0 = bf2f(pk[9999]) - logZ;
        float l1 = bf2f(pk[10000]) - logZ;
        float l2 = bf2f(pk[10001]) - logZ;
        st[0] = l0; st[1] = l1; st[2] = l1; st[3] = l2;
    }
}

// ---------- tail0: reduce partials + in-place expand+normalize / zero-fill ----------
__global__ __launch_bounds__(256) void tail0_norm(float* __restrict__ out,
                                                  const int* __restrict__ rowlist,
                                                  const int* __restrict__ cntbuf,
                                                  const float* __restrict__ ST,
                                                  const float* __restrict__ PART) {
    const int b = blockIdx.x, tid = threadIdx.x;
    const int cnt = cntbuf[0];
    const long row = rowlist[b];
    float* p = out + (size_t)row * 50257 + 10000;
    __shared__ float red[4];
    if (b < cnt) {
        float s = 0.f;
        for (int c = tid; c < 628; c += 256) s += PART[(size_t)b * 628 + c];
#pragma unroll
        for (int o = 32; o; o >>= 1) s += __shfl_xor(s, o);
        if ((tid & 63) == 0) red[tid >> 6] = s;
        __syncthreads();
        float Aa = __logf(red[0] + red[1] + red[2] + red[3]) - ST[row * 8 + 0];
        const u16* src = (const u16*)out + pack_base_tail(row);
        for (int k = 0; k < 5; k++) {
            float v[4][8];
#pragma unroll
            for (int g = 0; g < 4; g++) {
                int o = 2048 * g + tid * 8;
                if (o < 8000) {
                    u16x8 xv = *(const u16x8*)(src + 8000 * k + o);
#pragma unroll
                    for (int z = 0; z < 8; z++) v[g][z] = bf2f(xv[z]);
                }
            }
            __syncthreads();
#pragma unroll
            for (int g = 0; g < 4; g++) {
                int o = 2048 * g + tid * 8;
                if (o < 8000) {
                    int e = 8000 * k + o;
#pragma unroll
                    for (int z = 0; z < 8; z++) p[e + z] = v[g][z] - Aa;
                }
            }
            __syncthreads();
        }
    } else {
        float v0 = ST[row * 8 + 2], v1 = ST[row * 8 + 3];
        for (int e = tid; e < 40000; e += 256) p[e] = 0.f;
        if (tid == 0) { p[0] = v0; p[1] = v1; }
    }
}

// ---------- tail1: tiny GEMM + log_softmax + masked write for cols [50000,50257) ----------
__global__ __launch_bounds__(256) void tail1_kernel(float* __restrict__ out,
                                                    const int* __restrict__ tgt,
                                                    const u16* __restrict__ proj,
                                                    const u16* __restrict__ t1b,
                                                    const float* __restrict__ stats) {
    const int row = blockIdx.x, tid = threadIdx.x;
    float* p = out + (size_t)row * 50257 + 50000;
    int t = tgt[row];
    if (t < 50000) {
        for (int c = tid; c < 257; c += 256) p[c] = 0.f;
        return;
    }
    __shared__ float pr[256];
    __shared__ float lg[257];
    __shared__ float red[4];
    pr[tid] = bf2f(proj[(size_t)row * 1280 + 1024 + tid]);
    __syncthreads();
    for (int c = tid; c < 257; c += 256) {
        const u16* w = t1b + c * 256;
        float acc = 0.f;
        for (int k = 0; k < 256; k++) acc += bf2f(w[k]) * pr[k];
        lg[c] = acc;
    }
    __syncthreads();
    float s = 0.f;
    for (int c = tid; c < 257; c += 256) s += __expf(lg[c]);
#pragma unroll
    for (int o = 32; o; o >>= 1) s += __shfl_xor(s, o);
    if ((tid & 63) == 0) red[tid >> 6] = s;
    __syncthreads();
    float A = __logf(red[0] + red[1] + red[2] + red[3]) - stats[row * 8 + 1];  // logZ - prior1
    for (int c = tid; c < 257; c += 256) p[c] = lg[c] - A;
}

// ---------- workspace layout (bytes) ----------
#define OFF_XI    0UL              // 2048*1024*2    = 4,194,304
#define OFF_HEADW 4194304UL        // 10240*1024*2   = 20,971,520
#define OFF_TAB   25165824UL       // 1280*1024*2    = 2,621,440
#define OFF_T0B   27787264UL       // 40192*1024*2   = 82,313,216
#define OFF_T1B   110100480UL      // 257*256*2      = 131,584
#define OFF_PROJ  110232064UL      // 2048*1280*2    = 5,242,880
#define OFF_ST    115474944UL      // 2048*8*4       = 65,536
#define OFF_PART  115540480UL      // 2048*628*4     = 5,144,576
#define OFF_PARTH 120685056UL      // 2048*160*4     = 1,310,720
#define OFF_MAP   121995776UL      // 2048*4
#define OFF_CNT   122003968UL      // 64

extern "C" void kernel_launch(void* const* d_in, const int* in_sizes, int n_in,
                              void* d_out, int out_size, void* d_ws, size_t ws_size,
                              hipStream_t stream) {
    const float* x   = (const float*)d_in[0];
    const int*   tgt = (const int*)d_in[1];
    const float* hw  = (const float*)d_in[2];
    const float* t0a = (const float*)d_in[3];
    const float* t0b = (const float*)d_in[4];
    const float* t1a = (const float*)d_in[5];
    const float* t1b = (const float*)d_in[6];
    float* out = (float*)d_out;
    char* ws = (char*)d_ws;

    u16* XI     = (u16*)(ws + OFF_XI);
    u16* HW     = (u16*)(ws + OFF_HEADW);
    u16* TAB    = (u16*)(ws + OFF_TAB);
    u16* T0B    = (u16*)(ws + OFF_T0B);
    u16* T1B    = (u16*)(ws + OFF_T1B);
    u16* PROJ   = (u16*)(ws + OFF_PROJ);
    float* ST   = (float*)(ws + OFF_ST);
    float* PART = (float*)(ws + OFF_PART);
    float* PARTH = (float*)(ws + OFF_PARTH);
    int* MAP    = (int*)(ws + OFF_MAP);
    int* CNT    = (int*)(ws + OFF_CNT);

    // 1) all converts + pads (one kernel)
    cvt_all<<<2108, 256, 0, stream>>>(x, hw, t0a, t1a, t0b, t1b, XI, HW, TAB, T0B, T1B);

    // 2) row map (padded to 256)
    build_map<<<1, 256, 0, stream>>>(tgt, MAP, CNT);

    // 3) head GEMM (256^2 8-phase, XCD-swizzled): bf16 pack + exp partials
    gemm256p<0><<<dim3(8, 40), 512, 0, stream>>>(XI, HW, (u16*)d_out, nullptr, nullptr, PARTH);

    // 4) head: logZ + expand to f32 lp + stats
    head_norm<<<2048, 256, 0, stream>>>(out, ST, PARTH);

    // 5) proj GEMM: [xi @ t0a.T | xi @ t1a.T] -> bf16 (2048 x 1280)
    gemm_nt_bf16<<<dim3(16, 10), 256, 0, stream>>>(XI, 1024, TAB, 1024, PROJ, 1280L, 1024);

    // 6) tail0 GEMM (256^2 8-phase, XCD-swizzled, rowlist-gathered A)
    gemm256p<1><<<dim3(8, 157), 512, 0, stream>>>(PROJ, T0B, (u16*)d_out, MAP, CNT, PART);

    // 7) fused reduce + expand/normalize (masked) / zero-fill (unmasked)
    tail0_norm<<<2048, 256, 0, stream>>>(out, MAP, CNT, ST, PART);

    // 8) tail1
    tail1_kernel<<<2048, 256, 0, stream>>>(out, tgt, PROJ, T1B, ST);
}

// Round 10
// 546.195 us; speedup vs baseline: 1.1842x; 1.0382x over previous
//
#include <hip/hip_runtime.h>

typedef unsigned short u16;
typedef unsigned int u32;
typedef __attribute__((ext_vector_type(4))) float f32x4;
typedef __bf16 bf16x8 __attribute__((ext_vector_type(8)));
typedef __attribute__((ext_vector_type(8))) unsigned short u16x8;

// ---------- small helpers ----------
__device__ __forceinline__ u16 f2bf(float x) {
    u32 u = __builtin_bit_cast(u32, x);
    u += 0x7FFFu + ((u >> 16) & 1u);   // RNE
    return (u16)(u >> 16);
}
__device__ __forceinline__ float bf2f(u16 u) {
    return __builtin_bit_cast(float, ((u32)u) << 16);
}
__device__ __forceinline__ void gld_lds16(void* lds, const void* g) {
    __builtin_amdgcn_global_load_lds(
        (const __attribute__((address_space(1))) void*)g,
        (__attribute__((address_space(3))) void*)lds, 16, 0, 0);
}

// bf16 pack locations inside an output row (u16 index into d_out viewed as u16).
__device__ __forceinline__ size_t pack_base_tail(long row) {
    return (size_t)row * 100514 + 59936 - ((row * 2) & 7);
}
__device__ __forceinline__ size_t pack_base_head(long row) {
    return (size_t)row * 100514 + 20480 - ((row * 2) & 7);
}

__device__ __forceinline__ void cvt_range(const float* __restrict__ src,
                                          u16* __restrict__ dst, int n,
                                          int bloc, int nb) {
    int i0 = bloc * 1024 + threadIdx.x * 4;
    int stride = nb * 1024;
    if (src) {
        for (int i = i0; i < n; i += stride) {
            float4 v = *(const float4*)(src + i);
            ushort4 o;
            o.x = f2bf(v.x); o.y = f2bf(v.y); o.z = f2bf(v.z); o.w = f2bf(v.w);
            *(ushort4*)(dst + i) = o;
        }
    } else {
        ushort4 z = {0, 0, 0, 0};
        for (int i = i0; i < n; i += stride) *(ushort4*)(dst + i) = z;
    }
}

// ---------- launch 1: small converts + pads + row map ----------
// rowlist[0..cnt) = masked rows asc; rowlist[cnt..2048) = unmasked rows asc.
// cntbuf: [0]=cnt, [1]=cnt padded to 256
__global__ __launch_bounds__(256) void cvt1(const float* __restrict__ x,
                                            const float* __restrict__ hw,
                                            const float* __restrict__ t0a,
                                            const float* __restrict__ t1a,
                                            const float* __restrict__ t1b,
                                            const int* __restrict__ tgt,
                                            u16* __restrict__ XI, u16* __restrict__ HW,
                                            u16* __restrict__ TAB, u16* __restrict__ T1B,
                                            int* __restrict__ rowlist, int* __restrict__ cntbuf) {
    int b = blockIdx.x;
    if (b < 80)       { cvt_range(x,   XI,            2097152,  b,       80);  return; }
    if (b < 472)      { cvt_range(hw,  HW,            10242048, b - 80,  392); return; }
    if (b < 512)      { cvt_range(t0a, TAB,           1048576,  b - 472, 40);  return; }
    if (b < 522)      { cvt_range(t1a, TAB + 1048576, 262144,   b - 512, 10);  return; }
    if (b < 526)      { cvt_range(t1b, T1B,           65792,    b - 522, 4);   return; }
    if (b < 536)      { cvt_range(0,   HW + 10242048, 243712,   b - 526, 10);  return; }
    // b == 536: build row map
    __shared__ int cs[257];
    int t = threadIdx.x;
    int cnt_local = 0;
    int mk[8];
#pragma unroll
    for (int k = 0; k < 8; k++) {
        int tg = tgt[t * 8 + k];
        mk[k] = (tg >= 10000 && tg < 50000) ? 1 : 0;
        cnt_local += mk[k];
    }
    cs[t + 1] = cnt_local;
    __syncthreads();
    if (t == 0) {
        cs[0] = 0;
        for (int i = 1; i <= 256; i++) cs[i] += cs[i - 1];
        cntbuf[0] = cs[256];
        cntbuf[1] = (cs[256] + 255) & ~255;
    }
    __syncthreads();
    int cnt = cs[256];
    int offm = cs[t];
    int offu = cnt + (t * 8 - cs[t]);
#pragma unroll
    for (int k = 0; k < 8; k++) {
        if (mk[k]) rowlist[offm++] = t * 8 + k;
        else       rowlist[offu++] = t * 8 + k;
    }
}

// ---------- launch 2: proj GEMM (blocks 0..159) + t0b convert (160..1723) + pad ----------
__global__ __launch_bounds__(256) void proj_cvt(const u16* __restrict__ A,
                                                const u16* __restrict__ B,
                                                u16* __restrict__ Cb,
                                                const float* __restrict__ t0b,
                                                u16* __restrict__ T0B) {
    int b = blockIdx.x;
    if (b >= 160) {
        if (b < 1724) cvt_range(t0b, T0B, 40960000, b - 160, 1564);
        else          cvt_range(0, T0B + 40960000, 196608, b - 1724, 8);
        return;
    }
    // 128x128 NT bf16 GEMM (m97 structure): XI(2048x1024) @ TAB^T(1280x1024) -> PROJ bf16
    __shared__ u16 lA[128 * 32];
    __shared__ u16 lB[128 * 32];
    const int tid = threadIdx.x;
    const int lane = tid & 63, wv = tid >> 6;
    const int m0 = (b & 15) * 128, n0 = (b >> 4) * 128;

    const u16* gA0 = A + (size_t)(m0 + (tid >> 2)) * 1024 + (tid & 3) * 8;
    const u16* gB0 = B + (size_t)(n0 + (tid >> 2)) * 1024 + (tid & 3) * 8;
    char* dA = (char*)lA + wv * 1024;
    char* dB = (char*)lB + wv * 1024;

    f32x4 acc[4][4] = {};
    const int wm = wv >> 1, wn = wv & 1;
    const int lr = lane & 15;
    const int lk = (lane >> 4) * 8;

    for (int kt = 0; kt < 1024; kt += 32) {
        __syncthreads();
        gld_lds16(dA, gA0);
        gld_lds16(dA + 4096, gA0 + 64 * 1024);
        gld_lds16(dB, gB0);
        gld_lds16(dB + 4096, gB0 + 64 * 1024);
        gA0 += 32; gB0 += 32;
        __syncthreads();

        bf16x8 af[4], bfr[4];
#pragma unroll
        for (int i = 0; i < 4; i++) {
            af[i]  = *(const bf16x8*)(lA + (wm * 64 + i * 16 + lr) * 32 + lk);
            bfr[i] = *(const bf16x8*)(lB + (wn * 64 + i * 16 + lr) * 32 + lk);
        }
#pragma unroll
        for (int i = 0; i < 4; i++)
#pragma unroll
            for (int j = 0; j < 4; j++)
                acc[i][j] = __builtin_amdgcn_mfma_f32_16x16x32_bf16(af[i], bfr[j], acc[i][j], 0, 0, 0);
    }

    const int cr = (lane >> 4) * 4;
    const int cc = lane & 15;
#pragma unroll
    for (int i = 0; i < 4; i++) {
        int rbase = m0 + wm * 64 + i * 16 + cr;
#pragma unroll
        for (int j = 0; j < 4; j++) {
            int c = n0 + wn * 64 + j * 16 + cc;
#pragma unroll
            for (int q = 0; q < 4; q++)
                Cb[(size_t)(rbase + q) * 1280 + c] = f2bf(acc[i][j][q]);
        }
    }
}

// ---------- launch 3: head + tail0 GEMM, one dispatch ----------
// 256x256 BK=64 8-wave m201-style 8-phase NT bf16 GEMM (R9-verified body).
// y<40: head (A=XI rows direct, B=HW, pack->head, partials->PARTH stride 160)
// y>=40: tail (A=PROJ via rowlist, B=T0B, pack->tail, partials->PART stride 628)
// Per-portion XCD swizzle (portion sizes 320/1256; 320%8==0 keeps flat%8 mapping).
__global__ __launch_bounds__(512, 1) void gemm_all(const u16* __restrict__ XI,
                                                   const u16* __restrict__ PROJ,
                                                   const u16* __restrict__ HW,
                                                   const u16* __restrict__ T0B,
                                                   u16* __restrict__ outpk,
                                                   const int* __restrict__ rowlist,
                                                   const int* __restrict__ cntbuf,
                                                   float* __restrict__ parth,
                                                   float* __restrict__ part) {
    const bool tail = blockIdx.y >= 40;
    const int NY = tail ? 157 : 40;
    const int l = (blockIdx.y - (tail ? 40 : 0)) * 8 + blockIdx.x;
    const int w = (l & 7) * NY + (l >> 3);
    const int m0 = (w & 7) * 256, n0 = (w >> 3) * 256;
    if (tail && m0 >= cntbuf[1]) return;
    const u16* A = tail ? PROJ : XI;
    const u16* B = tail ? T0B : HW;
    __shared__ u16 lds[65536];
    const int tid = threadIdx.x;
    const int lane = tid & 63, wv = tid >> 6;
    const int wm = wv >> 2, wn = wv & 3;
    const int lr = lane & 15, hi = lane >> 4;

    const int rp = ((tid >> 7) << 4) + (tid & 15);
    const int kp = ((tid >> 4) & 7) * 8;
    const u16 *pA[2][2], *pB[2][2];
#pragma unroll
    for (int h = 0; h < 2; h++) {
#pragma unroll
        for (int c = 0; c < 2; c++) {
            int row = h * 128 + rp + c * 64;
            if (tail) pA[h][c] = A + (size_t)rowlist[m0 + row] * 1280 + kp;
            else      pA[h][c] = A + (size_t)(m0 + row) * 1024 + kp;
            pB[h][c] = B + (size_t)(n0 + row) * 1024 + kp;
        }
    }

    f32x4 acc[8][4] = {};
    bf16x8 Bf[4][2], Af[2][2];

    auto stA = [&](int s, int h, int t) {
        u16* d = lds + s * 16384 + h * 8192 + tid * 8;
        int ko = t * 64;
        gld_lds16(d, pA[h][0] + ko);
        gld_lds16(d + 4096, pA[h][1] + ko);
    };
    auto stB = [&](int s, int h, int t) {
        u16* d = lds + 32768 + s * 16384 + h * 8192 + tid * 8;
        int ko = t * 64;
        gld_lds16(d, pB[h][0] + ko);
        gld_lds16(d + 4096, pB[h][1] + ko);
    };
    auto rdB = [&](int s) {
        const u16* base = lds + 32768 + s * 16384 + (wn >> 1) * 8192 + (wn & 1) * 4096 + hi * 128 + lr * 8;
#pragma unroll
        for (int j = 0; j < 4; j++)
#pragma unroll
            for (int ks = 0; ks < 2; ks++)
                Bf[j][ks] = *(const bf16x8*)(base + j * 1024 + ks * 512);
    };
    auto rdA = [&](int s, int p) {
        const u16* base = lds + s * 16384 + wm * 8192 + p * 2048 + hi * 128 + lr * 8;
#pragma unroll
        for (int m = 0; m < 2; m++)
#pragma unroll
            for (int ks = 0; ks < 2; ks++)
                Af[m][ks] = *(const bf16x8*)(base + m * 1024 + ks * 512);
    };
    auto mf = [&](int p) {
        __builtin_amdgcn_s_setprio(1);
#pragma unroll
        for (int m = 0; m < 2; m++)
#pragma unroll
            for (int j = 0; j < 4; j++)
#pragma unroll
                for (int ks = 0; ks < 2; ks++)
                    acc[p * 2 + m][j] = __builtin_amdgcn_mfma_f32_16x16x32_bf16(
                        Af[m][ks], Bf[j][ks], acc[p * 2 + m][j], 0, 0, 0);
        __builtin_amdgcn_s_setprio(0);
    };

#define BAR_()   __builtin_amdgcn_s_barrier()
#define LGKM0_() do { asm volatile("s_waitcnt lgkmcnt(0)" ::: "memory"); \
                      __builtin_amdgcn_sched_barrier(0); } while (0)
#define VM4_()   asm volatile("s_waitcnt vmcnt(4)" ::: "memory")
#define VM0_()   asm volatile("s_waitcnt vmcnt(0)" ::: "memory")

    stA(0, 0, 0); stA(0, 1, 0); stB(0, 0, 0); stB(0, 1, 0);
    VM0_();
    stB(1, 0, 1); stB(1, 1, 1);
    BAR_();

    auto iter = [&](int t0, bool full) {
        // P1
        rdB(0); rdA(0, 0);
        stA(1, 0, t0 + 1);
        BAR_(); LGKM0_(); mf(0); BAR_();
        // P2
        rdA(0, 1);
        stA(1, 1, t0 + 1);
        __builtin_amdgcn_sched_barrier(0);
        if (full) stB(0, 0, t0 + 2);
        BAR_(); LGKM0_(); mf(1); BAR_();
        // P3
        rdA(0, 2);
        if (full) stB(0, 1, t0 + 2);
        BAR_(); LGKM0_(); mf(2); BAR_();
        // P4
        rdA(0, 3);
        if (full) { VM4_(); } else { VM0_(); }
        BAR_(); LGKM0_(); mf(3); BAR_();
        // P5
        rdB(1); rdA(1, 0);
        if (full) stA(0, 0, t0 + 2);
        BAR_(); LGKM0_(); mf(0); BAR_();
        // P6
        rdA(1, 1);
        if (full) { stA(0, 1, t0 + 2);
                    __builtin_amdgcn_sched_barrier(0);
                    stB(1, 0, t0 + 3); }
        BAR_(); LGKM0_(); mf(1); BAR_();
        // P7
        rdA(1, 2);
        if (full) stB(1, 1, t0 + 3);
        BAR_(); LGKM0_(); mf(2); BAR_();
        // P8
        rdA(1, 3);
        if (full) VM4_();
        BAR_(); LGKM0_(); mf(3); BAR_();
    };
#pragma unroll 1
    for (int i = 0; i < 7; i++) iter(2 * i, true);
    iter(14, false);

#undef BAR_
#undef LGKM0_
#undef VM4_
#undef VM0_

    const int cr = hi * 4, cc = lr;
    const int climit = tail ? 40000 : 10002;
    const int pstride = tail ? 628 : 160;
    float* pbuf = tail ? part : parth;
#pragma unroll
    for (int m = 0; m < 8; m++) {
#pragma unroll
        for (int q = 0; q < 4; q++) {
            int r = m0 + wm * 128 + m * 16 + cr + q;
            long orow = tail ? rowlist[r] : r;
            size_t base = tail ? pack_base_tail(orow) : pack_base_head(orow);
            u16* dst = outpk + base + n0 + wn * 64 + cc;
            float s = 0.f;
#pragma unroll
            for (int j = 0; j < 4; j++) {
                float v = acc[m][j][q];
                dst[j * 16] = f2bf(v);
                int col = n0 + wn * 64 + j * 16 + cc;
                s += (col < climit) ? __expf(v) : 0.f;
            }
            s += __shfl_xor(s, 1); s += __shfl_xor(s, 2);
            s += __shfl_xor(s, 4); s += __shfl_xor(s, 8);
            if (cc == 0) pbuf[(size_t)r * pstride + (n0 >> 6) + wn] = s;
        }
    }
}

// ---------- launch 4: all normalization, one block per compact slot ----------
// block b -> row rowlist[b]. Phases (syncthreads-ordered, hazards as before):
//  1) head: reduce PARTH -> logZh; priors from head pack; expand cols [0,10002)
//  2) tail0: b<cnt reduce PART -> expand cols [10000,50000); else zero-fill+priors
//  3) tail1: cols [50000,50257) masked compute / zero-fill
__global__ __launch_bounds__(256) void norm_all(float* __restrict__ out,
                                                const int* __restrict__ tgt,
                                                const int* __restrict__ rowlist,
                                                const int* __restrict__ cntbuf,
                                                const float* __restrict__ PARTH,
                                                const float* __restrict__ PART,
                                                const u16* __restrict__ proj,
                                                const u16* __restrict__ t1b) {
    const int b = blockIdx.x, tid = threadIdx.x;
    const int cnt = cntbuf[0];
    const long row = rowlist[b];
    __shared__ float red[4];
    __shared__ float pr[256];
    __shared__ float lg[257];
    float* p0 = out + (size_t)row * 50257;

    // --- phase 1: head ---
    float s = (tid < 160) ? PARTH[(size_t)row * 160 + tid] : 0.f;
#pragma unroll
    for (int o = 32; o; o >>= 1) s += __shfl_xor(s, o);
    if ((tid & 63) == 0) red[tid >> 6] = s;
    __syncthreads();
    float logZh = __logf(red[0] + red[1] + red[2] + red[3]);
    const u16* pkh = (const u16*)out + pack_base_head(row);
    float prior0 = bf2f(pkh[9999]) - logZh;
    float l1 = bf2f(pkh[10000]) - logZh;
    float l2 = bf2f(pkh[10001]) - logZh;
    for (int k = 0; k < 5; k++) {
        int c0 = k * 2048 + tid * 8;
        if (c0 + 8 <= 10002) {
            u16x8 xv = *(const u16x8*)(pkh + c0);
#pragma unroll
            for (int z = 0; z < 8; z++) p0[c0 + z] = bf2f(xv[z]) - logZh;
        } else if (c0 < 10002) {
            for (int z = 0; c0 + z < 10002; z++) p0[c0 + z] = bf2f(pkh[c0 + z]) - logZh;
        }
    }
    __syncthreads();

    // --- phase 2: tail0 ---
    float* p = p0 + 10000;
    if (b < cnt) {
        float s2 = 0.f;
        for (int c = tid; c < 628; c += 256) s2 += PART[(size_t)b * 628 + c];
#pragma unroll
        for (int o = 32; o; o >>= 1) s2 += __shfl_xor(s2, o);
        if ((tid & 63) == 0) red[tid >> 6] = s2;
        __syncthreads();
        float Aa = __logf(red[0] + red[1] + red[2] + red[3]) - prior0;
        const u16* src = (const u16*)out + pack_base_tail(row);
        for (int k = 0; k < 5; k++) {
            float v[4][8];
#pragma unroll
            for (int g = 0; g < 4; g++) {
                int o = 2048 * g + tid * 8;
                if (o < 8000) {
                    u16x8 xv = *(const u16x8*)(src + 8000 * k + o);
#pragma unroll
                    for (int z = 0; z < 8; z++) v[g][z] = bf2f(xv[z]);
                }
            }
            __syncthreads();
#pragma unroll
            for (int g = 0; g < 4; g++) {
                int o = 2048 * g + tid * 8;
                if (o < 8000) {
                    int e = 8000 * k + o;
#pragma unroll
                    for (int z = 0; z < 8; z++) p[e + z] = v[g][z] - Aa;
                }
            }
            __syncthreads();
        }
    } else {
        for (int e = tid; e < 40000; e += 256) p[e] = 0.f;
        if (tid == 0) { p[0] = l1; p[1] = l2; }
        __syncthreads();
    }

    // --- phase 3: tail1 (after tail pack fully consumed) ---
    float* p5 = p0 + 50000;
    int t = tgt[row];
    if (t < 50000) {
        for (int c = tid; c < 257; c += 256) p5[c] = 0.f;
        return;
    }
    pr[tid] = bf2f(proj[(size_t)row * 1280 + 1024 + tid]);
    __syncthreads();
    for (int c = tid; c < 257; c += 256) {
        const u16* wp = t1b + c * 256;
        float acc = 0.f;
        for (int k = 0; k < 256; k++) acc += bf2f(wp[k]) * pr[k];
        lg[c] = acc;
    }
    __syncthreads();
    float s1 = 0.f;
    for (int c = tid; c < 257; c += 256) s1 += __expf(lg[c]);
#pragma unroll
    for (int o = 32; o; o >>= 1) s1 += __shfl_xor(s1, o);
    if ((tid & 63) == 0) red[tid >> 6] = s1;
    __syncthreads();
    float A = __logf(red[0] + red[1] + red[2] + red[3]) - l1;  // logZ - prior1
    for (int c = tid; c < 257; c += 256) p5[c] = lg[c] - A;
}

// ---------- workspace layout (bytes) ----------
#define OFF_XI    0UL              // 2048*1024*2    = 4,194,304
#define OFF_HEADW 4194304UL        // 10240*1024*2   = 20,971,520
#define OFF_TAB   25165824UL       // 1280*1024*2    = 2,621,440
#define OFF_T0B   27787264UL       // 40192*1024*2   = 82,313,216
#define OFF_T1B   110100480UL      // 257*256*2      = 131,584
#define OFF_PROJ  110232064UL      // 2048*1280*2    = 5,242,880
#define OFF_PART  115474944UL      // 2048*628*4     = 5,144,576
#define OFF_PARTH 120619520UL      // 2048*160*4     = 1,310,720
#define OFF_MAP   121930240UL      // 2048*4
#define OFF_CNT   121938432UL      // 64

extern "C" void kernel_launch(void* const* d_in, const int* in_sizes, int n_in,
                              void* d_out, int out_size, void* d_ws, size_t ws_size,
                              hipStream_t stream) {
    const float* x   = (const float*)d_in[0];
    const int*   tgt = (const int*)d_in[1];
    const float* hw  = (const float*)d_in[2];
    const float* t0a = (const float*)d_in[3];
    const float* t0b = (const float*)d_in[4];
    const float* t1a = (const float*)d_in[5];
    const float* t1b = (const float*)d_in[6];
    float* out = (float*)d_out;
    char* ws = (char*)d_ws;

    u16* XI     = (u16*)(ws + OFF_XI);
    u16* HW     = (u16*)(ws + OFF_HEADW);
    u16* TAB    = (u16*)(ws + OFF_TAB);
    u16* T0B    = (u16*)(ws + OFF_T0B);
    u16* T1B    = (u16*)(ws + OFF_T1B);
    u16* PROJ   = (u16*)(ws + OFF_PROJ);
    float* PART = (float*)(ws + OFF_PART);
    float* PARTH = (float*)(ws + OFF_PARTH);
    int* MAP    = (int*)(ws + OFF_MAP);
    int* CNT    = (int*)(ws + OFF_CNT);

    // 1) small converts + pads + row map
    cvt1<<<537, 256, 0, stream>>>(x, hw, t0a, t1a, t1b, tgt, XI, HW, TAB, T1B, MAP, CNT);

    // 2) proj GEMM overlapped with t0b convert + pad
    proj_cvt<<<1732, 256, 0, stream>>>(XI, TAB, PROJ, t0b, T0B);

    // 3) head + tail0 GEMM in one dispatch (256^2 8-phase, XCD-swizzled per portion)
    gemm_all<<<dim3(8, 197), 512, 0, stream>>>(XI, PROJ, HW, T0B, (u16*)d_out, MAP, CNT, PARTH, PART);

    // 4) all normalization (head expand, tail0 expand/zero, tail1)
    norm_all<<<2048, 256, 0, stream>>>(out, tgt, MAP, CNT, PARTH, PART, PROJ, T1B);
}

// Round 11
// 537.358 us; speedup vs baseline: 1.2037x; 1.0164x over previous
//
#include <hip/hip_runtime.h>

typedef unsigned short u16;
typedef unsigned int u32;
typedef __attribute__((ext_vector_type(4))) float f32x4;
typedef __bf16 bf16x8 __attribute__((ext_vector_type(8)));
typedef __attribute__((ext_vector_type(8))) unsigned short u16x8;

// ---------- small helpers ----------
__device__ __forceinline__ u16 f2bf(float x) {
    u32 u = __builtin_bit_cast(u32, x);
    u += 0x7FFFu + ((u >> 16) & 1u);   // RNE
    return (u16)(u >> 16);
}
__device__ __forceinline__ float bf2f(u16 u) {
    return __builtin_bit_cast(float, ((u32)u) << 16);
}
__device__ __forceinline__ void gld_lds16(void* lds, const void* g) {
    __builtin_amdgcn_global_load_lds(
        (const __attribute__((address_space(1))) void*)g,
        (__attribute__((address_space(3))) void*)lds, 16, 0, 0);
}

// bf16 pack locations inside an output row (u16 index into d_out viewed as u16).
__device__ __forceinline__ size_t pack_base_tail(long row) {
    return (size_t)row * 100514 + 59936 - ((row * 2) & 7);
}
__device__ __forceinline__ size_t pack_base_head(long row) {
    return (size_t)row * 100514 + 20480 - ((row * 2) & 7);
}

__device__ __forceinline__ void cvt_range(const float* __restrict__ src,
                                          u16* __restrict__ dst, int n,
                                          int bloc, int nb) {
    int i0 = bloc * 1024 + threadIdx.x * 4;
    int stride = nb * 1024;
    if (src) {
        for (int i = i0; i < n; i += stride) {
            float4 v = *(const float4*)(src + i);
            ushort4 o;
            o.x = f2bf(v.x); o.y = f2bf(v.y); o.z = f2bf(v.z); o.w = f2bf(v.w);
            *(ushort4*)(dst + i) = o;
        }
    } else {
        ushort4 z = {0, 0, 0, 0};
        for (int i = i0; i < n; i += stride) *(ushort4*)(dst + i) = z;
    }
}

// ---------- launch 1: small converts + pads + row map ----------
// rowlist[0..cnt) = masked rows asc; rowlist[cnt..2048) = unmasked rows asc.
// cntbuf: [0]=cnt, [1]=cnt padded to 256
__global__ __launch_bounds__(256) void cvt1(const float* __restrict__ x,
                                            const float* __restrict__ hw,
                                            const float* __restrict__ t0a,
                                            const float* __restrict__ t1a,
                                            const float* __restrict__ t1b,
                                            const int* __restrict__ tgt,
                                            u16* __restrict__ XI, u16* __restrict__ HW,
                                            u16* __restrict__ TAB, u16* __restrict__ T1B,
                                            int* __restrict__ rowlist, int* __restrict__ cntbuf) {
    int b = blockIdx.x;
    if (b < 80)       { cvt_range(x,   XI,            2097152,  b,       80);  return; }
    if (b < 472)      { cvt_range(hw,  HW,            10242048, b - 80,  392); return; }
    if (b < 512)      { cvt_range(t0a, TAB,           1048576,  b - 472, 40);  return; }
    if (b < 522)      { cvt_range(t1a, TAB + 1048576, 262144,   b - 512, 10);  return; }
    if (b < 526)      { cvt_range(t1b, T1B,           65792,    b - 522, 4);   return; }
    if (b < 536)      { cvt_range(0,   HW + 10242048, 243712,   b - 526, 10);  return; }
    // b == 536: build row map
    __shared__ int cs[257];
    int t = threadIdx.x;
    int cnt_local = 0;
    int mk[8];
#pragma unroll
    for (int k = 0; k < 8; k++) {
        int tg = tgt[t * 8 + k];
        mk[k] = (tg >= 10000 && tg < 50000) ? 1 : 0;
        cnt_local += mk[k];
    }
    cs[t + 1] = cnt_local;
    __syncthreads();
    if (t == 0) {
        cs[0] = 0;
        for (int i = 1; i <= 256; i++) cs[i] += cs[i - 1];
        cntbuf[0] = cs[256];
        cntbuf[1] = (cs[256] + 255) & ~255;
    }
    __syncthreads();
    int cnt = cs[256];
    int offm = cs[t];
    int offu = cnt + (t * 8 - cs[t]);
#pragma unroll
    for (int k = 0; k < 8; k++) {
        if (mk[k]) rowlist[offm++] = t * 8 + k;
        else       rowlist[offu++] = t * 8 + k;
    }
}

// ---------- launch 2: proj GEMM (blocks 0..159) + t0b convert (160..1723) + pad ----------
__global__ __launch_bounds__(256) void proj_cvt(const u16* __restrict__ A,
                                                const u16* __restrict__ B,
                                                u16* __restrict__ Cb,
                                                const float* __restrict__ t0b,
                                                u16* __restrict__ T0B) {
    int b = blockIdx.x;
    if (b >= 160) {
        if (b < 1724) cvt_range(t0b, T0B, 40960000, b - 160, 1564);
        else          cvt_range(0, T0B + 40960000, 196608, b - 1724, 8);
        return;
    }
    // 128x128 NT bf16 GEMM (m97 structure): XI(2048x1024) @ TAB^T(1280x1024) -> PROJ bf16
    __shared__ u16 lA[128 * 32];
    __shared__ u16 lB[128 * 32];
    const int tid = threadIdx.x;
    const int lane = tid & 63, wv = tid >> 6;
    const int m0 = (b & 15) * 128, n0 = (b >> 4) * 128;

    const u16* gA0 = A + (size_t)(m0 + (tid >> 2)) * 1024 + (tid & 3) * 8;
    const u16* gB0 = B + (size_t)(n0 + (tid >> 2)) * 1024 + (tid & 3) * 8;
    char* dA = (char*)lA + wv * 1024;
    char* dB = (char*)lB + wv * 1024;

    f32x4 acc[4][4] = {};
    const int wm = wv >> 1, wn = wv & 1;
    const int lr = lane & 15;
    const int lk = (lane >> 4) * 8;

    for (int kt = 0; kt < 1024; kt += 32) {
        __syncthreads();
        gld_lds16(dA, gA0);
        gld_lds16(dA + 4096, gA0 + 64 * 1024);
        gld_lds16(dB, gB0);
        gld_lds16(dB + 4096, gB0 + 64 * 1024);
        gA0 += 32; gB0 += 32;
        __syncthreads();

        bf16x8 af[4], bfr[4];
#pragma unroll
        for (int i = 0; i < 4; i++) {
            af[i]  = *(const bf16x8*)(lA + (wm * 64 + i * 16 + lr) * 32 + lk);
            bfr[i] = *(const bf16x8*)(lB + (wn * 64 + i * 16 + lr) * 32 + lk);
        }
#pragma unroll
        for (int i = 0; i < 4; i++)
#pragma unroll
            for (int j = 0; j < 4; j++)
                acc[i][j] = __builtin_amdgcn_mfma_f32_16x16x32_bf16(af[i], bfr[j], acc[i][j], 0, 0, 0);
    }

    const int cr = (lane >> 4) * 4;
    const int cc = lane & 15;
#pragma unroll
    for (int i = 0; i < 4; i++) {
        int rbase = m0 + wm * 64 + i * 16 + cr;
#pragma unroll
        for (int j = 0; j < 4; j++) {
            int c = n0 + wn * 64 + j * 16 + cc;
#pragma unroll
            for (int q = 0; q < 4; q++)
                Cb[(size_t)(rbase + q) * 1280 + c] = f2bf(acc[i][j][q]);
        }
    }
}

// ---------- launches 3+4: head / tail0 GEMM (compile-time specialized) ----------
// 256x256 BK=64 8-wave m201-style 8-phase NT bf16 GEMM (R9-verified body).
// TAIL=0: A=XI rows direct, B=HW, pack->head, partials->stride 160
// TAIL=1: A=PROJ via rowlist, B=T0B, pack->tail, partials->stride 628
template <int TAIL>
__global__ __launch_bounds__(512, 1) void gemm256p(const u16* __restrict__ A,
                                                   const u16* __restrict__ B,
                                                   u16* __restrict__ outpk,
                                                   const int* __restrict__ rowlist,
                                                   const int* __restrict__ cntbuf,
                                                   float* __restrict__ part) {
    const int NY = TAIL ? 157 : 40;
    const int l = blockIdx.y * 8 + blockIdx.x;
    const int w = (l & 7) * NY + (l >> 3);
    const int m0 = (w & 7) * 256, n0 = (w >> 3) * 256;
    if (TAIL) { if (m0 >= cntbuf[1]) return; }
    __shared__ u16 lds[65536];
    const int tid = threadIdx.x;
    const int lane = tid & 63, wv = tid >> 6;
    const int wm = wv >> 2, wn = wv & 3;
    const int lr = lane & 15, hi = lane >> 4;

    const int rp = ((tid >> 7) << 4) + (tid & 15);
    const int kp = ((tid >> 4) & 7) * 8;
    const u16 *pA[2][2], *pB[2][2];
#pragma unroll
    for (int h = 0; h < 2; h++) {
#pragma unroll
        for (int c = 0; c < 2; c++) {
            int row = h * 128 + rp + c * 64;
            if (TAIL) pA[h][c] = A + (size_t)rowlist[m0 + row] * 1280 + kp;
            else      pA[h][c] = A + (size_t)(m0 + row) * 1024 + kp;
            pB[h][c] = B + (size_t)(n0 + row) * 1024 + kp;
        }
    }

    f32x4 acc[8][4] = {};
    bf16x8 Bf[4][2], Af[2][2];

    auto stA = [&](int s, int h, int t) {
        u16* d = lds + s * 16384 + h * 8192 + tid * 8;
        int ko = t * 64;
        gld_lds16(d, pA[h][0] + ko);
        gld_lds16(d + 4096, pA[h][1] + ko);
    };
    auto stB = [&](int s, int h, int t) {
        u16* d = lds + 32768 + s * 16384 + h * 8192 + tid * 8;
        int ko = t * 64;
        gld_lds16(d, pB[h][0] + ko);
        gld_lds16(d + 4096, pB[h][1] + ko);
    };
    auto rdB = [&](int s) {
        const u16* base = lds + 32768 + s * 16384 + (wn >> 1) * 8192 + (wn & 1) * 4096 + hi * 128 + lr * 8;
#pragma unroll
        for (int j = 0; j < 4; j++)
#pragma unroll
            for (int ks = 0; ks < 2; ks++)
                Bf[j][ks] = *(const bf16x8*)(base + j * 1024 + ks * 512);
    };
    auto rdA = [&](int s, int p) {
        const u16* base = lds + s * 16384 + wm * 8192 + p * 2048 + hi * 128 + lr * 8;
#pragma unroll
        for (int m = 0; m < 2; m++)
#pragma unroll
            for (int ks = 0; ks < 2; ks++)
                Af[m][ks] = *(const bf16x8*)(base + m * 1024 + ks * 512);
    };
    auto mf = [&](int p) {
        __builtin_amdgcn_s_setprio(1);
#pragma unroll
        for (int m = 0; m < 2; m++)
#pragma unroll
            for (int j = 0; j < 4; j++)
#pragma unroll
                for (int ks = 0; ks < 2; ks++)
                    acc[p * 2 + m][j] = __builtin_amdgcn_mfma_f32_16x16x32_bf16(
                        Af[m][ks], Bf[j][ks], acc[p * 2 + m][j], 0, 0, 0);
        __builtin_amdgcn_s_setprio(0);
    };

#define BAR_()   __builtin_amdgcn_s_barrier()
#define LGKM0_() do { asm volatile("s_waitcnt lgkmcnt(0)" ::: "memory"); \
                      __builtin_amdgcn_sched_barrier(0); } while (0)
#define VM4_()   asm volatile("s_waitcnt vmcnt(4)" ::: "memory")
#define VM0_()   asm volatile("s_waitcnt vmcnt(0)" ::: "memory")

    stA(0, 0, 0); stA(0, 1, 0); stB(0, 0, 0); stB(0, 1, 0);
    VM0_();
    stB(1, 0, 1); stB(1, 1, 1);
    BAR_();

    auto iter = [&](int t0, bool full) {
        // P1
        rdB(0); rdA(0, 0);
        stA(1, 0, t0 + 1);
        BAR_(); LGKM0_(); mf(0); BAR_();
        // P2
        rdA(0, 1);
        stA(1, 1, t0 + 1);
        __builtin_amdgcn_sched_barrier(0);
        if (full) stB(0, 0, t0 + 2);
        BAR_(); LGKM0_(); mf(1); BAR_();
        // P3
        rdA(0, 2);
        if (full) stB(0, 1, t0 + 2);
        BAR_(); LGKM0_(); mf(2); BAR_();
        // P4
        rdA(0, 3);
        if (full) { VM4_(); } else { VM0_(); }
        BAR_(); LGKM0_(); mf(3); BAR_();
        // P5
        rdB(1); rdA(1, 0);
        if (full) stA(0, 0, t0 + 2);
        BAR_(); LGKM0_(); mf(0); BAR_();
        // P6
        rdA(1, 1);
        if (full) { stA(0, 1, t0 + 2);
                    __builtin_amdgcn_sched_barrier(0);
                    stB(1, 0, t0 + 3); }
        BAR_(); LGKM0_(); mf(1); BAR_();
        // P7
        rdA(1, 2);
        if (full) stB(1, 1, t0 + 3);
        BAR_(); LGKM0_(); mf(2); BAR_();
        // P8
        rdA(1, 3);
        if (full) VM4_();
        BAR_(); LGKM0_(); mf(3); BAR_();
    };
#pragma unroll 1
    for (int i = 0; i < 7; i++) iter(2 * i, true);
    iter(14, false);

#undef BAR_
#undef LGKM0_
#undef VM4_
#undef VM0_

    const int cr = hi * 4, cc = lr;
    const int climit = TAIL ? 40000 : 10002;
    const int pstride = TAIL ? 628 : 160;
#pragma unroll
    for (int m = 0; m < 8; m++) {
#pragma unroll
        for (int q = 0; q < 4; q++) {
            int r = m0 + wm * 128 + m * 16 + cr + q;
            long orow = TAIL ? rowlist[r] : r;
            size_t base = TAIL ? pack_base_tail(orow) : pack_base_head(orow);
            u16* dst = outpk + base + n0 + wn * 64 + cc;
            float s = 0.f;
#pragma unroll
            for (int j = 0; j < 4; j++) {
                float v = acc[m][j][q];
                dst[j * 16] = f2bf(v);
                int col = n0 + wn * 64 + j * 16 + cc;
                s += (col < climit) ? __expf(v) : 0.f;
            }
            s += __shfl_xor(s, 1); s += __shfl_xor(s, 2);
            s += __shfl_xor(s, 4); s += __shfl_xor(s, 8);
            if (cc == 0) part[(size_t)r * pstride + (n0 >> 6) + wn] = s;
        }
    }
}

// ---------- launch 5: all normalization, one block per compact slot ----------
__global__ __launch_bounds__(256) void norm_all(float* __restrict__ out,
                                                const int* __restrict__ tgt,
                                                const int* __restrict__ rowlist,
                                                const int* __restrict__ cntbuf,
                                                const float* __restrict__ PARTH,
                                                const float* __restrict__ PART,
                                                const u16* __restrict__ proj,
                                                const u16* __restrict__ t1b) {
    const int b = blockIdx.x, tid = threadIdx.x;
    const int cnt = cntbuf[0];
    const long row = rowlist[b];
    __shared__ float red[4];
    __shared__ float pr[256];
    __shared__ float lg[257];
    float* p0 = out + (size_t)row * 50257;

    // --- phase 1: head ---
    float s = (tid < 160) ? PARTH[(size_t)row * 160 + tid] : 0.f;
#pragma unroll
    for (int o = 32; o; o >>= 1) s += __shfl_xor(s, o);
    if ((tid & 63) == 0) red[tid >> 6] = s;
    __syncthreads();
    float logZh = __logf(red[0] + red[1] + red[2] + red[3]);
    const u16* pkh = (const u16*)out + pack_base_head(row);
    float prior0 = bf2f(pkh[9999]) - logZh;
    float l1 = bf2f(pkh[10000]) - logZh;
    float l2 = bf2f(pkh[10001]) - logZh;
    for (int k = 0; k < 5; k++) {
        int c0 = k * 2048 + tid * 8;
        if (c0 + 8 <= 10002) {
            u16x8 xv = *(const u16x8*)(pkh + c0);
#pragma unroll
            for (int z = 0; z < 8; z++) p0[c0 + z] = bf2f(xv[z]) - logZh;
        } else if (c0 < 10002) {
            for (int z = 0; c0 + z < 10002; z++) p0[c0 + z] = bf2f(pkh[c0 + z]) - logZh;
        }
    }
    __syncthreads();

    // --- phase 2: tail0 ---
    float* p = p0 + 10000;
    if (b < cnt) {
        float s2 = 0.f;
        for (int c = tid; c < 628; c += 256) s2 += PART[(size_t)b * 628 + c];
#pragma unroll
        for (int o = 32; o; o >>= 1) s2 += __shfl_xor(s2, o);
        if ((tid & 63) == 0) red[tid >> 6] = s2;
        __syncthreads();
        float Aa = __logf(red[0] + red[1] + red[2] + red[3]) - prior0;
        const u16* src = (const u16*)out + pack_base_tail(row);
        for (int k = 0; k < 5; k++) {
            float v[4][8];
#pragma unroll
            for (int g = 0; g < 4; g++) {
                int o = 2048 * g + tid * 8;
                if (o < 8000) {
                    u16x8 xv = *(const u16x8*)(src + 8000 * k + o);
#pragma unroll
                    for (int z = 0; z < 8; z++) v[g][z] = bf2f(xv[z]);
                }
            }
            __syncthreads();
#pragma unroll
            for (int g = 0; g < 4; g++) {
                int o = 2048 * g + tid * 8;
                if (o < 8000) {
                    int e = 8000 * k + o;
#pragma unroll
                    for (int z = 0; z < 8; z++) p[e + z] = v[g][z] - Aa;
                }
            }
            __syncthreads();
        }
    } else {
        for (int e = tid; e < 40000; e += 256) p[e] = 0.f;
        if (tid == 0) { p[0] = l1; p[1] = l2; }
        __syncthreads();
    }

    // --- phase 3: tail1 ---
    float* p5 = p0 + 50000;
    int t = tgt[row];
    if (t < 50000) {
        for (int c = tid; c < 257; c += 256) p5[c] = 0.f;
        return;
    }
    pr[tid] = bf2f(proj[(size_t)row * 1280 + 1024 + tid]);
    __syncthreads();
    for (int c = tid; c < 257; c += 256) {
        const u16* wp = t1b + c * 256;
        float acc = 0.f;
        for (int k = 0; k < 256; k++) acc += bf2f(wp[k]) * pr[k];
        lg[c] = acc;
    }
    __syncthreads();
    float s1 = 0.f;
    for (int c = tid; c < 257; c += 256) s1 += __expf(lg[c]);
#pragma unroll
    for (int o = 32; o; o >>= 1) s1 += __shfl_xor(s1, o);
    if ((tid & 63) == 0) red[tid >> 6] = s1;
    __syncthreads();
    float A = __logf(red[0] + red[1] + red[2] + red[3]) - l1;  // logZ - prior1
    for (int c = tid; c < 257; c += 256) p5[c] = lg[c] - A;
}

// ---------- workspace layout (bytes) ----------
#define OFF_XI    0UL              // 2048*1024*2    = 4,194,304
#define OFF_HEADW 4194304UL        // 10240*1024*2   = 20,971,520
#define OFF_TAB   25165824UL       // 1280*1024*2    = 2,621,440
#define OFF_T0B   27787264UL       // 40192*1024*2   = 82,313,216
#define OFF_T1B   110100480UL      // 257*256*2      = 131,584
#define OFF_PROJ  110232064UL      // 2048*1280*2    = 5,242,880
#define OFF_PART  115474944UL      // 2048*628*4     = 5,144,576
#define OFF_PARTH 120619520UL      // 2048*160*4     = 1,310,720
#define OFF_MAP   121930240UL      // 2048*4
#define OFF_CNT   121938432UL      // 64

extern "C" void kernel_launch(void* const* d_in, const int* in_sizes, int n_in,
                              void* d_out, int out_size, void* d_ws, size_t ws_size,
                              hipStream_t stream) {
    const float* x   = (const float*)d_in[0];
    const int*   tgt = (const int*)d_in[1];
    const float* hw  = (const float*)d_in[2];
    const float* t0a = (const float*)d_in[3];
    const float* t0b = (const float*)d_in[4];
    const float* t1a = (const float*)d_in[5];
    const float* t1b = (const float*)d_in[6];
    float* out = (float*)d_out;
    char* ws = (char*)d_ws;

    u16* XI     = (u16*)(ws + OFF_XI);
    u16* HW     = (u16*)(ws + OFF_HEADW);
    u16* TAB    = (u16*)(ws + OFF_TAB);
    u16* T0B    = (u16*)(ws + OFF_T0B);
    u16* T1B    = (u16*)(ws + OFF_T1B);
    u16* PROJ   = (u16*)(ws + OFF_PROJ);
    float* PART = (float*)(ws + OFF_PART);
    float* PARTH = (float*)(ws + OFF_PARTH);
    int* MAP    = (int*)(ws + OFF_MAP);
    int* CNT    = (int*)(ws + OFF_CNT);

    // 1) small converts + pads + row map
    cvt1<<<537, 256, 0, stream>>>(x, hw, t0a, t1a, t1b, tgt, XI, HW, TAB, T1B, MAP, CNT);

    // 2) proj GEMM overlapped with t0b convert + pad
    proj_cvt<<<1732, 256, 0, stream>>>(XI, TAB, PROJ, t0b, T0B);

    // 3) head GEMM (256^2 8-phase, XCD-swizzled): bf16 pack + exp partials
    gemm256p<0><<<dim3(8, 40), 512, 0, stream>>>(XI, HW, (u16*)d_out, nullptr, nullptr, PARTH);

    // 4) tail0 GEMM (256^2 8-phase, XCD-swizzled, rowlist-gathered A)
    gemm256p<1><<<dim3(8, 157), 512, 0, stream>>>(PROJ, T0B, (u16*)d_out, MAP, CNT, PART);

    // 5) all normalization (head expand, tail0 expand/zero, tail1)
    norm_all<<<2048, 256, 0, stream>>>(out, tgt, MAP, CNT, PARTH, PART, PROJ, T1B);
}

// Round 12
// 506.322 us; speedup vs baseline: 1.2775x; 1.0613x over previous
//
#include <hip/hip_runtime.h>

typedef unsigned short u16;
typedef unsigned int u32;
typedef __attribute__((ext_vector_type(4))) float f32x4;
typedef __bf16 bf16x8 __attribute__((ext_vector_type(8)));
typedef __attribute__((ext_vector_type(8))) unsigned short u16x8;

// ---------- small helpers ----------
__device__ __forceinline__ u16 f2bf(float x) {
    u32 u = __builtin_bit_cast(u32, x);
    u += 0x7FFFu + ((u >> 16) & 1u);   // RNE
    return (u16)(u >> 16);
}
__device__ __forceinline__ float bf2f(u16 u) {
    return __builtin_bit_cast(float, ((u32)u) << 16);
}
__device__ __forceinline__ void gld_lds16(void* lds, const void* g) {
    __builtin_amdgcn_global_load_lds(
        (const __attribute__((address_space(1))) void*)g,
        (__attribute__((address_space(3))) void*)lds, 16, 0, 0);
}

// bf16 pack locations inside an output row (u16 index into d_out viewed as u16).
__device__ __forceinline__ size_t pack_base_tail(long row) {
    return (size_t)row * 100514 + 59936 - ((row * 2) & 7);
}
__device__ __forceinline__ size_t pack_base_head(long row) {
    return (size_t)row * 100514 + 20480 - ((row * 2) & 7);
}

__device__ __forceinline__ void cvt_range(const float* __restrict__ src,
                                          u16* __restrict__ dst, int n,
                                          int bloc, int nb) {
    int i0 = bloc * 1024 + threadIdx.x * 4;
    int stride = nb * 1024;
    if (src) {
        for (int i = i0; i < n; i += stride) {
            float4 v = *(const float4*)(src + i);
            ushort4 o;
            o.x = f2bf(v.x); o.y = f2bf(v.y); o.z = f2bf(v.z); o.w = f2bf(v.w);
            *(ushort4*)(dst + i) = o;
        }
    } else {
        ushort4 z = {0, 0, 0, 0};
        for (int i = i0; i < n; i += stride) *(ushort4*)(dst + i) = z;
    }
}
__device__ __forceinline__ void cvt_range512(const float* __restrict__ src,
                                             u16* __restrict__ dst, int n,
                                             int bloc, int nb) {
    int i0 = bloc * 2048 + threadIdx.x * 4;
    int stride = nb * 2048;
    if (src) {
        for (int i = i0; i < n; i += stride) {
            float4 v = *(const float4*)(src + i);
            ushort4 o;
            o.x = f2bf(v.x); o.y = f2bf(v.y); o.z = f2bf(v.z); o.w = f2bf(v.w);
            *(ushort4*)(dst + i) = o;
        }
    } else {
        ushort4 z = {0, 0, 0, 0};
        for (int i = i0; i < n; i += stride) *(ushort4*)(dst + i) = z;
    }
}

// ---------- launch 1: small converts + pads + row map ----------
// rowlist[0..cnt) = masked rows asc; rowlist[cnt..2048) = unmasked rows asc.
// cntbuf: [0]=cnt, [1]=cnt padded to 256
__global__ __launch_bounds__(256) void cvt1(const float* __restrict__ x,
                                            const float* __restrict__ hw,
                                            const float* __restrict__ t0a,
                                            const float* __restrict__ t1a,
                                            const float* __restrict__ t1b,
                                            const int* __restrict__ tgt,
                                            u16* __restrict__ XI, u16* __restrict__ HW,
                                            u16* __restrict__ TAB, u16* __restrict__ T1B,
                                            int* __restrict__ rowlist, int* __restrict__ cntbuf) {
    int b = blockIdx.x;
    if (b < 80)       { cvt_range(x,   XI,            2097152,  b,       80);  return; }
    if (b < 472)      { cvt_range(hw,  HW,            10242048, b - 80,  392); return; }
    if (b < 512)      { cvt_range(t0a, TAB,           1048576,  b - 472, 40);  return; }
    if (b < 522)      { cvt_range(t1a, TAB + 1048576, 262144,   b - 512, 10);  return; }
    if (b < 526)      { cvt_range(t1b, T1B,           65792,    b - 522, 4);   return; }
    if (b < 536)      { cvt_range(0,   HW + 10242048, 243712,   b - 526, 10);  return; }
    // b == 536: build row map
    __shared__ int cs[257];
    int t = threadIdx.x;
    int cnt_local = 0;
    int mk[8];
#pragma unroll
    for (int k = 0; k < 8; k++) {
        int tg = tgt[t * 8 + k];
        mk[k] = (tg >= 10000 && tg < 50000) ? 1 : 0;
        cnt_local += mk[k];
    }
    cs[t + 1] = cnt_local;
    __syncthreads();
    if (t == 0) {
        cs[0] = 0;
        for (int i = 1; i <= 256; i++) cs[i] += cs[i - 1];
        cntbuf[0] = cs[256];
        cntbuf[1] = (cs[256] + 255) & ~255;
    }
    __syncthreads();
    int cnt = cs[256];
    int offm = cs[t];
    int offu = cnt + (t * 8 - cs[t]);
#pragma unroll
    for (int k = 0; k < 8; k++) {
        if (mk[k]) rowlist[offm++] = t * 8 + k;
        else       rowlist[offu++] = t * 8 + k;
    }
}

// ---------- launch 2: proj GEMM + head GEMM + t0b convert, one 512-thread dispatch ----------
// y<5: proj (A=XI, B=TAB, plain bf16 out, NY=5); y in [5,45): head (A=XI, B=HW,
// pack->head + partials, NY=40); y>=45: t0b convert + pad (576 blocks).
// GEMM body = R9/R11-verified 256x256 BK=64 8-phase; runtime flag only touches
// B pointer + epilogue (hot loop identical for both portions).
__global__ __launch_bounds__(512, 1) void fused2(const u16* __restrict__ XI,
                                                 const u16* __restrict__ TAB,
                                                 const u16* __restrict__ HW,
                                                 u16* __restrict__ PROJ,
                                                 u16* __restrict__ outpk,
                                                 float* __restrict__ parth,
                                                 const float* __restrict__ t0b,
                                                 u16* __restrict__ T0B) {
    const int y = blockIdx.y;
    if (y >= 45) {
        int bc = (y - 45) * 8 + blockIdx.x;   // 0..575
        if (bc < 568) cvt_range512(t0b, T0B, 40960000, bc, 568);
        else          cvt_range512(0, T0B + 40960000, 196608, bc - 568, 8);
        return;
    }
    const bool proj = y < 5;
    const int NY = proj ? 5 : 40;
    const int l = (proj ? y : y - 5) * 8 + blockIdx.x;
    const int w = (l & 7) * NY + (l >> 3);
    const int m0 = (w & 7) * 256, n0 = (w >> 3) * 256;
    const u16* B = proj ? TAB : HW;
    __shared__ u16 lds[65536];
    const int tid = threadIdx.x;
    const int lane = tid & 63, wv = tid >> 6;
    const int wm = wv >> 2, wn = wv & 3;
    const int lr = lane & 15, hi = lane >> 4;

    const int rp = ((tid >> 7) << 4) + (tid & 15);
    const int kp = ((tid >> 4) & 7) * 8;
    const u16 *pA[2][2], *pB[2][2];
#pragma unroll
    for (int h = 0; h < 2; h++) {
#pragma unroll
        for (int c = 0; c < 2; c++) {
            int row = h * 128 + rp + c * 64;
            pA[h][c] = XI + (size_t)(m0 + row) * 1024 + kp;
            pB[h][c] = B + (size_t)(n0 + row) * 1024 + kp;
        }
    }

    f32x4 acc[8][4] = {};
    bf16x8 Bf[4][2], Af[2][2];

    auto stA = [&](int s, int h, int t) {
        u16* d = lds + s * 16384 + h * 8192 + tid * 8;
        int ko = t * 64;
        gld_lds16(d, pA[h][0] + ko);
        gld_lds16(d + 4096, pA[h][1] + ko);
    };
    auto stB = [&](int s, int h, int t) {
        u16* d = lds + 32768 + s * 16384 + h * 8192 + tid * 8;
        int ko = t * 64;
        gld_lds16(d, pB[h][0] + ko);
        gld_lds16(d + 4096, pB[h][1] + ko);
    };
    auto rdB = [&](int s) {
        const u16* base = lds + 32768 + s * 16384 + (wn >> 1) * 8192 + (wn & 1) * 4096 + hi * 128 + lr * 8;
#pragma unroll
        for (int j = 0; j < 4; j++)
#pragma unroll
            for (int ks = 0; ks < 2; ks++)
                Bf[j][ks] = *(const bf16x8*)(base + j * 1024 + ks * 512);
    };
    auto rdA = [&](int s, int p) {
        const u16* base = lds + s * 16384 + wm * 8192 + p * 2048 + hi * 128 + lr * 8;
#pragma unroll
        for (int m = 0; m < 2; m++)
#pragma unroll
            for (int ks = 0; ks < 2; ks++)
                Af[m][ks] = *(const bf16x8*)(base + m * 1024 + ks * 512);
    };
    auto mf = [&](int p) {
        __builtin_amdgcn_s_setprio(1);
#pragma unroll
        for (int m = 0; m < 2; m++)
#pragma unroll
            for (int j = 0; j < 4; j++)
#pragma unroll
                for (int ks = 0; ks < 2; ks++)
                    acc[p * 2 + m][j] = __builtin_amdgcn_mfma_f32_16x16x32_bf16(
                        Af[m][ks], Bf[j][ks], acc[p * 2 + m][j], 0, 0, 0);
        __builtin_amdgcn_s_setprio(0);
    };

#define BAR_()   __builtin_amdgcn_s_barrier()
#define LGKM0_() do { asm volatile("s_waitcnt lgkmcnt(0)" ::: "memory"); \
                      __builtin_amdgcn_sched_barrier(0); } while (0)
#define VM4_()   asm volatile("s_waitcnt vmcnt(4)" ::: "memory")
#define VM0_()   asm volatile("s_waitcnt vmcnt(0)" ::: "memory")

    stA(0, 0, 0); stA(0, 1, 0); stB(0, 0, 0); stB(0, 1, 0);
    VM0_();
    stB(1, 0, 1); stB(1, 1, 1);
    BAR_();

    auto iter = [&](int t0, bool full) {
        rdB(0); rdA(0, 0);
        stA(1, 0, t0 + 1);
        BAR_(); LGKM0_(); mf(0); BAR_();
        rdA(0, 1);
        stA(1, 1, t0 + 1);
        __builtin_amdgcn_sched_barrier(0);
        if (full) stB(0, 0, t0 + 2);
        BAR_(); LGKM0_(); mf(1); BAR_();
        rdA(0, 2);
        if (full) stB(0, 1, t0 + 2);
        BAR_(); LGKM0_(); mf(2); BAR_();
        rdA(0, 3);
        if (full) { VM4_(); } else { VM0_(); }
        BAR_(); LGKM0_(); mf(3); BAR_();
        rdB(1); rdA(1, 0);
        if (full) stA(0, 0, t0 + 2);
        BAR_(); LGKM0_(); mf(0); BAR_();
        rdA(1, 1);
        if (full) { stA(0, 1, t0 + 2);
                    __builtin_amdgcn_sched_barrier(0);
                    stB(1, 0, t0 + 3); }
        BAR_(); LGKM0_(); mf(1); BAR_();
        rdA(1, 2);
        if (full) stB(1, 1, t0 + 3);
        BAR_(); LGKM0_(); mf(2); BAR_();
        rdA(1, 3);
        if (full) VM4_();
        BAR_(); LGKM0_(); mf(3); BAR_();
    };
#pragma unroll 1
    for (int i = 0; i < 7; i++) iter(2 * i, true);
    iter(14, false);

#undef BAR_
#undef LGKM0_
#undef VM4_
#undef VM0_

    const int cr = hi * 4, cc = lr;
    if (proj) {
#pragma unroll
        for (int m = 0; m < 8; m++)
#pragma unroll
            for (int q = 0; q < 4; q++) {
                int r = m0 + wm * 128 + m * 16 + cr + q;
#pragma unroll
                for (int j = 0; j < 4; j++)
                    PROJ[(size_t)r * 1280 + n0 + wn * 64 + j * 16 + cc] = f2bf(acc[m][j][q]);
            }
        return;
    }
#pragma unroll
    for (int m = 0; m < 8; m++) {
#pragma unroll
        for (int q = 0; q < 4; q++) {
            int r = m0 + wm * 128 + m * 16 + cr + q;
            u16* dst = outpk + pack_base_head((long)r) + n0 + wn * 64 + cc;
            float s = 0.f;
#pragma unroll
            for (int j = 0; j < 4; j++) {
                float v = acc[m][j][q];
                dst[j * 16] = f2bf(v);
                int col = n0 + wn * 64 + j * 16 + cc;
                s += (col < 10002) ? __expf(v) : 0.f;
            }
            s += __shfl_xor(s, 1); s += __shfl_xor(s, 2);
            s += __shfl_xor(s, 4); s += __shfl_xor(s, 8);
            if (cc == 0) parth[(size_t)r * 160 + (n0 >> 6) + wn] = s;
        }
    }
}

// ---------- launch 3: tail0 GEMM (compile-time specialized, R11-verified) ----------
template <int TAIL>
__global__ __launch_bounds__(512, 1) void gemm256p(const u16* __restrict__ A,
                                                   const u16* __restrict__ B,
                                                   u16* __restrict__ outpk,
                                                   const int* __restrict__ rowlist,
                                                   const int* __restrict__ cntbuf,
                                                   float* __restrict__ part) {
    const int NY = TAIL ? 157 : 40;
    const int l = blockIdx.y * 8 + blockIdx.x;
    const int w = (l & 7) * NY + (l >> 3);
    const int m0 = (w & 7) * 256, n0 = (w >> 3) * 256;
    if (TAIL) { if (m0 >= cntbuf[1]) return; }
    __shared__ u16 lds[65536];
    const int tid = threadIdx.x;
    const int lane = tid & 63, wv = tid >> 6;
    const int wm = wv >> 2, wn = wv & 3;
    const int lr = lane & 15, hi = lane >> 4;

    const int rp = ((tid >> 7) << 4) + (tid & 15);
    const int kp = ((tid >> 4) & 7) * 8;
    const u16 *pA[2][2], *pB[2][2];
#pragma unroll
    for (int h = 0; h < 2; h++) {
#pragma unroll
        for (int c = 0; c < 2; c++) {
            int row = h * 128 + rp + c * 64;
            if (TAIL) pA[h][c] = A + (size_t)rowlist[m0 + row] * 1280 + kp;
            else      pA[h][c] = A + (size_t)(m0 + row) * 1024 + kp;
            pB[h][c] = B + (size_t)(n0 + row) * 1024 + kp;
        }
    }

    f32x4 acc[8][4] = {};
    bf16x8 Bf[4][2], Af[2][2];

    auto stA = [&](int s, int h, int t) {
        u16* d = lds + s * 16384 + h * 8192 + tid * 8;
        int ko = t * 64;
        gld_lds16(d, pA[h][0] + ko);
        gld_lds16(d + 4096, pA[h][1] + ko);
    };
    auto stB = [&](int s, int h, int t) {
        u16* d = lds + 32768 + s * 16384 + h * 8192 + tid * 8;
        int ko = t * 64;
        gld_lds16(d, pB[h][0] + ko);
        gld_lds16(d + 4096, pB[h][1] + ko);
    };
    auto rdB = [&](int s) {
        const u16* base = lds + 32768 + s * 16384 + (wn >> 1) * 8192 + (wn & 1) * 4096 + hi * 128 + lr * 8;
#pragma unroll
        for (int j = 0; j < 4; j++)
#pragma unroll
            for (int ks = 0; ks < 2; ks++)
                Bf[j][ks] = *(const bf16x8*)(base + j * 1024 + ks * 512);
    };
    auto rdA = [&](int s, int p) {
        const u16* base = lds + s * 16384 + wm * 8192 + p * 2048 + hi * 128 + lr * 8;
#pragma unroll
        for (int m = 0; m < 2; m++)
#pragma unroll
            for (int ks = 0; ks < 2; ks++)
                Af[m][ks] = *(const bf16x8*)(base + m * 1024 + ks * 512);
    };
    auto mf = [&](int p) {
        __builtin_amdgcn_s_setprio(1);
#pragma unroll
        for (int m = 0; m < 2; m++)
#pragma unroll
            for (int j = 0; j < 4; j++)
#pragma unroll
                for (int ks = 0; ks < 2; ks++)
                    acc[p * 2 + m][j] = __builtin_amdgcn_mfma_f32_16x16x32_bf16(
                        Af[m][ks], Bf[j][ks], acc[p * 2 + m][j], 0, 0, 0);
        __builtin_amdgcn_s_setprio(0);
    };

#define BAR_()   __builtin_amdgcn_s_barrier()
#define LGKM0_() do { asm volatile("s_waitcnt lgkmcnt(0)" ::: "memory"); \
                      __builtin_amdgcn_sched_barrier(0); } while (0)
#define VM4_()   asm volatile("s_waitcnt vmcnt(4)" ::: "memory")
#define VM0_()   asm volatile("s_waitcnt vmcnt(0)" ::: "memory")

    stA(0, 0, 0); stA(0, 1, 0); stB(0, 0, 0); stB(0, 1, 0);
    VM0_();
    stB(1, 0, 1); stB(1, 1, 1);
    BAR_();

    auto iter = [&](int t0, bool full) {
        rdB(0); rdA(0, 0);
        stA(1, 0, t0 + 1);
        BAR_(); LGKM0_(); mf(0); BAR_();
        rdA(0, 1);
        stA(1, 1, t0 + 1);
        __builtin_amdgcn_sched_barrier(0);
        if (full) stB(0, 0, t0 + 2);
        BAR_(); LGKM0_(); mf(1); BAR_();
        rdA(0, 2);
        if (full) stB(0, 1, t0 + 2);
        BAR_(); LGKM0_(); mf(2); BAR_();
        rdA(0, 3);
        if (full) { VM4_(); } else { VM0_(); }
        BAR_(); LGKM0_(); mf(3); BAR_();
        rdB(1); rdA(1, 0);
        if (full) stA(0, 0, t0 + 2);
        BAR_(); LGKM0_(); mf(0); BAR_();
        rdA(1, 1);
        if (full) { stA(0, 1, t0 + 2);
                    __builtin_amdgcn_sched_barrier(0);
                    stB(1, 0, t0 + 3); }
        BAR_(); LGKM0_(); mf(1); BAR_();
        rdA(1, 2);
        if (full) stB(1, 1, t0 + 3);
        BAR_(); LGKM0_(); mf(2); BAR_();
        rdA(1, 3);
        if (full) VM4_();
        BAR_(); LGKM0_(); mf(3); BAR_();
    };
#pragma unroll 1
    for (int i = 0; i < 7; i++) iter(2 * i, true);
    iter(14, false);

#undef BAR_
#undef LGKM0_
#undef VM4_
#undef VM0_

    const int cr = hi * 4, cc = lr;
    const int climit = TAIL ? 40000 : 10002;
    const int pstride = TAIL ? 628 : 160;
#pragma unroll
    for (int m = 0; m < 8; m++) {
#pragma unroll
        for (int q = 0; q < 4; q++) {
            int r = m0 + wm * 128 + m * 16 + cr + q;
            long orow = TAIL ? rowlist[r] : r;
            size_t base = TAIL ? pack_base_tail(orow) : pack_base_head(orow);
            u16* dst = outpk + base + n0 + wn * 64 + cc;
            float s = 0.f;
#pragma unroll
            for (int j = 0; j < 4; j++) {
                float v = acc[m][j][q];
                dst[j * 16] = f2bf(v);
                int col = n0 + wn * 64 + j * 16 + cc;
                s += (col < climit) ? __expf(v) : 0.f;
            }
            s += __shfl_xor(s, 1); s += __shfl_xor(s, 2);
            s += __shfl_xor(s, 4); s += __shfl_xor(s, 8);
            if (cc == 0) part[(size_t)r * pstride + (n0 >> 6) + wn] = s;
        }
    }
}

// ---------- launch 4: all normalization, one block per compact slot ----------
__global__ __launch_bounds__(256) void norm_all(float* __restrict__ out,
                                                const int* __restrict__ tgt,
                                                const int* __restrict__ rowlist,
                                                const int* __restrict__ cntbuf,
                                                const float* __restrict__ PARTH,
                                                const float* __restrict__ PART,
                                                const u16* __restrict__ proj,
                                                const u16* __restrict__ t1b) {
    const int b = blockIdx.x, tid = threadIdx.x;
    const int cnt = cntbuf[0];
    const long row = rowlist[b];
    __shared__ float red[4];
    __shared__ float pr[256];
    __shared__ float lg[257];
    float* p0 = out + (size_t)row * 50257;

    // --- phase 1: head ---
    float s = (tid < 160) ? PARTH[(size_t)row * 160 + tid] : 0.f;
#pragma unroll
    for (int o = 32; o; o >>= 1) s += __shfl_xor(s, o);
    if ((tid & 63) == 0) red[tid >> 6] = s;
    __syncthreads();
    float logZh = __logf(red[0] + red[1] + red[2] + red[3]);
    const u16* pkh = (const u16*)out + pack_base_head(row);
    float prior0 = bf2f(pkh[9999]) - logZh;
    float l1 = bf2f(pkh[10000]) - logZh;
    float l2 = bf2f(pkh[10001]) - logZh;
    for (int k = 0; k < 5; k++) {
        int c0 = k * 2048 + tid * 8;
        if (c0 + 8 <= 10002) {
            u16x8 xv = *(const u16x8*)(pkh + c0);
#pragma unroll
            for (int z = 0; z < 8; z++) p0[c0 + z] = bf2f(xv[z]) - logZh;
        } else if (c0 < 10002) {
            for (int z = 0; c0 + z < 10002; z++) p0[c0 + z] = bf2f(pkh[c0 + z]) - logZh;
        }
    }
    __syncthreads();

    // --- phase 2: tail0 ---
    float* p = p0 + 10000;
    if (b < cnt) {
        float s2 = 0.f;
        for (int c = tid; c < 628; c += 256) s2 += PART[(size_t)b * 628 + c];
#pragma unroll
        for (int o = 32; o; o >>= 1) s2 += __shfl_xor(s2, o);
        if ((tid & 63) == 0) red[tid >> 6] = s2;
        __syncthreads();
        float Aa = __logf(red[0] + red[1] + red[2] + red[3]) - prior0;
        const u16* src = (const u16*)out + pack_base_tail(row);
        for (int k = 0; k < 5; k++) {
            float v[4][8];
#pragma unroll
            for (int g = 0; g < 4; g++) {
                int o = 2048 * g + tid * 8;
                if (o < 8000) {
                    u16x8 xv = *(const u16x8*)(src + 8000 * k + o);
#pragma unroll
                    for (int z = 0; z < 8; z++) v[g][z] = bf2f(xv[z]);
                }
            }
            __syncthreads();
#pragma unroll
            for (int g = 0; g < 4; g++) {
                int o = 2048 * g + tid * 8;
                if (o < 8000) {
                    int e = 8000 * k + o;
#pragma unroll
                    for (int z = 0; z < 8; z++) p[e + z] = v[g][z] - Aa;
                }
            }
            __syncthreads();
        }
    } else {
        for (int e = tid; e < 40000; e += 256) p[e] = 0.f;
        if (tid == 0) { p[0] = l1; p[1] = l2; }
        __syncthreads();
    }

    // --- phase 3: tail1 ---
    float* p5 = p0 + 50000;
    int t = tgt[row];
    if (t < 50000) {
        for (int c = tid; c < 257; c += 256) p5[c] = 0.f;
        return;
    }
    pr[tid] = bf2f(proj[(size_t)row * 1280 + 1024 + tid]);
    __syncthreads();
    for (int c = tid; c < 257; c += 256) {
        const u16* wp = t1b + c * 256;
        float acc = 0.f;
        for (int k = 0; k < 256; k++) acc += bf2f(wp[k]) * pr[k];
        lg[c] = acc;
    }
    __syncthreads();
    float s1 = 0.f;
    for (int c = tid; c < 257; c += 256) s1 += __expf(lg[c]);
#pragma unroll
    for (int o = 32; o; o >>= 1) s1 += __shfl_xor(s1, o);
    if ((tid & 63) == 0) red[tid >> 6] = s1;
    __syncthreads();
    float A = __logf(red[0] + red[1] + red[2] + red[3]) - l1;  // logZ - prior1
    for (int c = tid; c < 257; c += 256) p5[c] = lg[c] - A;
}

// ---------- workspace layout (bytes) ----------
#define OFF_XI    0UL              // 2048*1024*2    = 4,194,304
#define OFF_HEADW 4194304UL        // 10240*1024*2   = 20,971,520
#define OFF_TAB   25165824UL       // 1280*1024*2    = 2,621,440
#define OFF_T0B   27787264UL       // 40192*1024*2   = 82,313,216
#define OFF_T1B   110100480UL      // 257*256*2      = 131,584
#define OFF_PROJ  110232064UL      // 2048*1280*2    = 5,242,880
#define OFF_PART  115474944UL      // 2048*628*4     = 5,144,576
#define OFF_PARTH 120619520UL      // 2048*160*4     = 1,310,720
#define OFF_MAP   121930240UL      // 2048*4
#define OFF_CNT   121938432UL      // 64

extern "C" void kernel_launch(void* const* d_in, const int* in_sizes, int n_in,
                              void* d_out, int out_size, void* d_ws, size_t ws_size,
                              hipStream_t stream) {
    const float* x   = (const float*)d_in[0];
    const int*   tgt = (const int*)d_in[1];
    const float* hw  = (const float*)d_in[2];
    const float* t0a = (const float*)d_in[3];
    const float* t0b = (const float*)d_in[4];
    const float* t1a = (const float*)d_in[5];
    const float* t1b = (const float*)d_in[6];
    float* out = (float*)d_out;
    char* ws = (char*)d_ws;

    u16* XI     = (u16*)(ws + OFF_XI);
    u16* HW     = (u16*)(ws + OFF_HEADW);
    u16* TAB    = (u16*)(ws + OFF_TAB);
    u16* T0B    = (u16*)(ws + OFF_T0B);
    u16* T1B    = (u16*)(ws + OFF_T1B);
    u16* PROJ   = (u16*)(ws + OFF_PROJ);
    float* PART = (float*)(ws + OFF_PART);
    float* PARTH = (float*)(ws + OFF_PARTH);
    int* MAP    = (int*)(ws + OFF_MAP);
    int* CNT    = (int*)(ws + OFF_CNT);

    // 1) small converts + pads + row map
    cvt1<<<537, 256, 0, stream>>>(x, hw, t0a, t1a, t1b, tgt, XI, HW, TAB, T1B, MAP, CNT);

    // 2) proj GEMM + head GEMM + t0b convert, one dispatch
    fused2<<<dim3(8, 117), 512, 0, stream>>>(XI, TAB, HW, PROJ, (u16*)d_out, PARTH, t0b, T0B);

    // 3) tail0 GEMM (256^2 8-phase, XCD-swizzled, rowlist-gathered A)
    gemm256p<1><<<dim3(8, 157), 512, 0, stream>>>(PROJ, T0B, (u16*)d_out, MAP, CNT, PART);

    // 4) all normalization (head expand, tail0 expand/zero, tail1)
    norm_all<<<2048, 256, 0, stream>>>(out, tgt, MAP, CNT, PARTH, PART, PROJ, T1B);
}